// Round 8
// baseline (561.064 us; speedup 1.0000x reference)
//
#include <hip/hip_runtime.h>
#include <stdint.h>

#define NDRUG 20000
#define NDIS  40000
#define HID   128
#define NE    150000
#define NREL  7
#define RPSTR (NDIS + 1)
#define NS_TOT (NREL * RPSTR)

typedef unsigned short ushort_t;
typedef __attribute__((ext_vector_type(8))) short bf16x8;
typedef __attribute__((ext_vector_type(4))) float f32x4;
typedef const __attribute__((address_space(1))) void gv_t;
typedef __attribute__((address_space(3))) void lv_t;

__device__ __forceinline__ ushort_t f2bf(float f) {
  unsigned u = __float_as_uint(f);
  u += 0x7FFFu + ((u >> 16) & 1u);          // RNE
  return (ushort_t)(u >> 16);
}
__device__ __forceinline__ float bf2f(ushort_t h) {
  return __uint_as_float(((unsigned)h) << 16);
}

// ============ dual-job bf16 MFMA GEMM: C = A[M,K] @ BT[N,K]^T ============
// 128x256 tile, 4 waves (2m x 2n), global_load_lds staging (16B), 64B LDS rows.
struct GemmJob { const ushort_t* A; const ushort_t* BT; const float* bias; void* C; int M, N; };

template<bool BIAS, bool RELU, bool BF16OUT>
__global__ __launch_bounds__(256) void gemm_dual(GemmJob j0, GemmJob j1, int gx0, int K)
{
  __shared__ ushort_t As[128 * 32];   // 8 KB
  __shared__ ushort_t Bs[256 * 32];   // 16 KB
  const bool first = blockIdx.x < (unsigned)gx0;
  const GemmJob J = first ? j0 : j1;
  const int bx = first ? blockIdx.x : blockIdx.x - gx0;
  const int m0 = bx * 128;
  const int n0 = blockIdx.y * 256;
  if (n0 >= J.N) return;   // uniform exit before any sync
  const int tid = threadIdx.x;
  const int wave = tid >> 6, lane = tid & 63;
  const int wm = wave & 1, wn = wave >> 1;
  const int l15 = lane & 15, lk = lane >> 4;

  const int rowS = wave * 16 + (lane >> 2);
  const int chunk = (lane & 3) * 8;
  const ushort_t* ga0 = J.A + (size_t)min(m0 + rowS, J.M - 1) * K + chunk;
  const ushort_t* ga1 = J.A + (size_t)min(m0 + rowS + 64, J.M - 1) * K + chunk;
  const ushort_t* gb[4];
  #pragma unroll
  for (int i = 0; i < 4; ++i)
    gb[i] = J.BT + (size_t)min(n0 + rowS + i * 64, J.N - 1) * K + chunk;

  f32x4 acc[4][8] = {};

  for (int k0 = 0; k0 < K; k0 += 32) {
    __syncthreads();
    __builtin_amdgcn_global_load_lds((gv_t*)(ga0 + k0), (lv_t*)(As + wave * 512), 16, 0, 0);
    __builtin_amdgcn_global_load_lds((gv_t*)(ga1 + k0), (lv_t*)(As + wave * 512 + 2048), 16, 0, 0);
    #pragma unroll
    for (int i = 0; i < 4; ++i)
      __builtin_amdgcn_global_load_lds((gv_t*)(gb[i] + k0), (lv_t*)(Bs + wave * 512 + i * 2048), 16, 0, 0);
    __syncthreads();

    bf16x8 af[4], bfg[8];
    #pragma unroll
    for (int m = 0; m < 4; ++m)
      af[m] = *reinterpret_cast<const bf16x8*>(&As[(wm * 64 + m * 16 + l15) * 32 + lk * 8]);
    #pragma unroll
    for (int n = 0; n < 8; ++n)
      bfg[n] = *reinterpret_cast<const bf16x8*>(&Bs[(wn * 128 + n * 16 + l15) * 32 + lk * 8]);
    #pragma unroll
    for (int m = 0; m < 4; ++m)
      #pragma unroll
      for (int n = 0; n < 8; ++n)
        acc[m][n] = __builtin_amdgcn_mfma_f32_16x16x32_bf16(af[m], bfg[n], acc[m][n], 0, 0, 0);
  }

  #pragma unroll
  for (int m = 0; m < 4; ++m) {
    int rbase = m0 + wm * 64 + m * 16 + lk * 4;
    #pragma unroll
    for (int n = 0; n < 8; ++n) {
      int col = n0 + wn * 128 + n * 16 + l15;
      if (col >= J.N) continue;
      float bv = 0.f;
      if (BIAS) bv = J.bias[col];
      #pragma unroll
      for (int j = 0; j < 4; ++j) {
        int row = rbase + j;
        if (row >= J.M) continue;
        float v = acc[m][n][j] + bv;
        if (RELU) v = fmaxf(v, 0.f);
        if (BF16OUT) ((ushort_t*)J.C)[(size_t)row * J.N + col] = f2bf(v);
        else         ((float*)J.C)[(size_t)row * J.N + col] = v;
      }
    }
  }
}

// ================= weight prep (two outputs in one dispatch) =================
__global__ void build_wcat2(const float* __restrict__ WA, ushort_t* __restrict__ outA,
                            int ncolA, int4 relsA,
                            const float* __restrict__ WB, ushort_t* __restrict__ outB,
                            int ncolB, int4 relsB, int K)
{
  int id = blockIdx.x * 256 + threadIdx.x;
  const float* W; ushort_t* out; int ncol; int4 rels;
  int totA = K * ncolA;
  if (id < totA) { W = WA; out = outA; ncol = ncolA; rels = relsA; }
  else {
    id -= totA;
    if (id >= K * ncolB) return;
    W = WB; out = outB; ncol = ncolB; rels = relsB;
  }
  int k = id / ncol, c = id - k * ncol;
  int rr = (&rels.x)[c >> 7];
  out[(size_t)c * K + k] = f2bf(W[((size_t)rr * K + k) * HID + (c & 127)]);
}

// wv[slot][k] = sum_j W[r][k][j] * a[r][j]   (slot<7: src, else dst)
__global__ __launch_bounds__(256) void wvec_kernel(
    const float* __restrict__ Wsrc, const float* __restrict__ as_,
    const float* __restrict__ Wdst, const float* __restrict__ ad_,
    float* __restrict__ wv, int K)
{
  int slot = blockIdx.x;
  int r = slot % NREL;
  const float* W = (slot < NREL ? Wsrc : Wdst) + (size_t)r * K * HID;
  const float* a = (slot < NREL ? as_ : ad_) + r * HID;
  int wave = threadIdx.x >> 6, lane = threadIdx.x & 63;
  int k = blockIdx.y * 4 + wave;
  if (k >= K) return;
  float s = W[(size_t)k * HID + lane] * a[lane]
          + W[(size_t)k * HID + 64 + lane] * a[64 + lane];
  #pragma unroll
  for (int off = 32; off; off >>= 1) s += __shfl_xor(s, off);
  if (lane == 0) wv[slot * 256 + k] = s;
}

// ================= f32 -> bf16 convert (two tensors, one dispatch) =================
__global__ void cvt2_f32_bf16(const float* __restrict__ inA, ushort_t* __restrict__ outA, int n8A,
                              const float* __restrict__ inB, ushort_t* __restrict__ outB, int n8B)
{
  int i = blockIdx.x * 256 + threadIdx.x;
  const float* in; ushort_t* out;
  if (i < n8A) { in = inA; out = outA; }
  else {
    i -= n8A;
    if (i >= n8B) return;
    in = inB; out = outB;
  }
  float4 a = reinterpret_cast<const float4*>(in)[2 * i];
  float4 b = reinterpret_cast<const float4*>(in)[2 * i + 1];
  ushort_t r[8] = {f2bf(a.x), f2bf(a.y), f2bf(a.z), f2bf(a.w),
                   f2bf(b.x), f2bf(b.y), f2bf(b.z), f2bf(b.w)};
  reinterpret_cast<uint4*>(out)[i] = *reinterpret_cast<uint4*>(r);
}

// ================= batched alpha GEMV, both node types in one dispatch =================
struct AlphaJobs { int wslot[8]; int outOff[8]; };

template<int K>
__global__ __launch_bounds__(256) void alpha_dual(
    const ushort_t* __restrict__ XD, const ushort_t* __restrict__ XI,
    const float* __restrict__ wv, float* __restrict__ outBase,
    AlphaJobs jd, AlphaJobs ji, int gbD)
{
  const bool isD = blockIdx.x < (unsigned)gbD;
  const ushort_t* X = isD ? XD : XI;
  const int N = isD ? NDRUG : NDIS;
  const AlphaJobs jobs = isD ? jd : ji;
  int i = (isD ? blockIdx.x : blockIdx.x - gbD) * 256 + threadIdx.x;
  if (i >= N) return;
  float acc[8];
  #pragma unroll
  for (int v = 0; v < 8; ++v) acc[v] = 0.f;
  const ushort_t* xp = X + (size_t)i * K;
  for (int k = 0; k < K; k += 8) {
    uint4 u = *reinterpret_cast<const uint4*>(xp + k);
    unsigned uu[4] = {u.x, u.y, u.z, u.w};
    float xf[8];
    #pragma unroll
    for (int q = 0; q < 4; ++q) {
      xf[2 * q]     = __uint_as_float(uu[q] << 16);
      xf[2 * q + 1] = __uint_as_float(uu[q] & 0xFFFF0000u);
    }
    #pragma unroll
    for (int v = 0; v < 8; ++v) {
      const float* wp = wv + jobs.wslot[v] * 256 + k;
      #pragma unroll
      for (int q = 0; q < 8; ++q) acc[v] += xf[q] * wp[q];
    }
  }
  #pragma unroll
  for (int v = 0; v < 8; ++v) outBase[jobs.outOff[v] + i] = acc[v];
}

// ================= CSR build =================
struct RelIdx { const int* src[NREL]; const int* dst[NREL]; };
struct NdArr  { int nd[NREL]; };

__global__ void zero_ints(int* __restrict__ p, int n) {
  int i = blockIdx.x * 256 + threadIdx.x;
  if (i < n) p[i] = 0;
}
__global__ void hist_k(RelIdx ri, int* __restrict__ counts) {
  int e = blockIdx.x * 256 + threadIdx.x;
  int r = blockIdx.y;
  if (e >= NE) return;
  atomicAdd(&counts[r * RPSTR + ri.dst[r][e]], 1);
}
__global__ __launch_bounds__(256) void scan_blk(const int* __restrict__ in,
                                                int* __restrict__ partial,
                                                int* __restrict__ bsum, int n)
{
  __shared__ int ts[256];
  int t = threadIdx.x;
  int base = blockIdx.x * 1024 + t * 4;
  int v[4];
  #pragma unroll
  for (int i = 0; i < 4; ++i) v[i] = (base + i < n) ? in[base + i] : 0;
  int s = v[0] + v[1] + v[2] + v[3];
  ts[t] = s; __syncthreads();
  for (int off = 1; off < 256; off <<= 1) {
    int x = (t >= off) ? ts[t - off] : 0;
    __syncthreads();
    ts[t] += x;
    __syncthreads();
  }
  int run = ts[t] - s;
  #pragma unroll
  for (int i = 0; i < 4; ++i) {
    if (base + i < n) partial[base + i] = run;
    run += v[i];
  }
  if (t == 255) bsum[blockIdx.x] = ts[255];
}
// block bx: rowptr/cursor[bx*1024 + i] = partial[...] + sum(bsum[0..bx))
__global__ __launch_bounds__(512) void scan_fin(const int* __restrict__ partial,
                                                const int* __restrict__ bsum,
                                                int* __restrict__ rowptr,
                                                int* __restrict__ cursor, int n)
{
  __shared__ int ts[512];
  int t = threadIdx.x;
  ts[t] = (t < (int)blockIdx.x) ? bsum[t] : 0;   // nb <= 512
  __syncthreads();
  #pragma unroll
  for (int off = 256; off; off >>= 1) {
    if (t < off) ts[t] += ts[t + off];
    __syncthreads();
  }
  int base = ts[0];
  #pragma unroll
  for (int i = 0; i < 2; ++i) {
    int idx = blockIdx.x * 1024 + t + i * 512;
    if (idx < n) {
      int v = partial[idx] + base;
      rowptr[idx] = v; cursor[idx] = v;
    }
  }
}
__global__ void fill_k(RelIdx ri, int* __restrict__ cursor, int* __restrict__ colsrc) {
  int e = blockIdx.x * 256 + threadIdx.x;
  int r = blockIdx.y;
  if (e >= NE) return;
  int d = ri.dst[r][e];
  int pos = atomicAdd(&cursor[r * RPSTR + d], 1);
  colsrc[pos] = ri.src[r][e];
}

// ==== per-(rel,dst) softmax: pack[i] = {normalized coef, src-bits} ====
__global__ __launch_bounds__(256) void coef_k(
    const int* __restrict__ rowptr, const int* __restrict__ colsrc,
    float2* __restrict__ pack, const float* __restrict__ alphaB, NdArr nds)
{
  int d = blockIdx.x * 256 + threadIdx.x;
  int r = blockIdx.y;
  if (d >= nds.nd[r]) return;
  int beg = rowptr[r * RPSTR + d], end = rowptr[r * RPSTR + d + 1];
  if (beg == end) return;
  const float ad = alphaB[(NREL + r) * NDIS + d];
  const float* as = alphaB + (size_t)r * NDIS;
  int deg = end - beg;
  if (deg <= 16) {
    float av[16]; int sv[16];
    float m = -1e30f;
    #pragma unroll
    for (int i = 0; i < 16; ++i) {
      float a = -1e30f; int s = 0;
      if (i < deg) {
        s = colsrc[beg + i];
        a = as[s] + ad;
        a = a > 0.f ? a : 0.2f * a;
      }
      av[i] = a; sv[i] = s;
      m = fmaxf(m, a);
    }
    float sum = 0.f;
    #pragma unroll
    for (int i = 0; i < 16; ++i) {
      if (i < deg) {
        float ex = __expf(av[i] - m);
        av[i] = ex;
        sum += ex;
      }
    }
    float inv = 1.f / (sum + 1e-16f);
    #pragma unroll
    for (int i = 0; i < 16; ++i) {
      if (i < deg) {
        float2 pk; pk.x = av[i] * inv; pk.y = __int_as_float(sv[i]);
        pack[beg + i] = pk;
      }
    }
  } else {
    float m = -1e30f;
    for (int i = beg; i < end; ++i) {
      float a = as[colsrc[i]] + ad;
      a = a > 0.f ? a : 0.2f * a;
      m = fmaxf(m, a);
    }
    float sum = 0.f;
    for (int i = beg; i < end; ++i) {
      int s = colsrc[i];
      float a = as[s] + ad;
      a = a > 0.f ? a : 0.2f * a;
      float ex = __expf(a - m);
      float2 pk; pk.x = ex; pk.y = __int_as_float(s);
      pack[i] = pk;
      sum += ex;
    }
    float inv = 1.f / (sum + 1e-16f);
    for (int i = beg; i < end; ++i) ((float*)pack)[2 * (size_t)i] *= inv;
  }
}

// ==== PV gather (exact r4 layout): full wave per dst, 2 cols/lane, 4-edge unroll ====
struct PvRel { int rel; int rowptr_off; const ushort_t* hs; int hst; int hoff; };
struct PvParams { PvRel dr[3]; PvRel di[4]; };

template<bool RELU>
__global__ __launch_bounds__(256) void pv_multi(
    PvParams P, const int* __restrict__ rowptr, const float2* __restrict__ pack,
    const float* __restrict__ bias,
    ushort_t* __restrict__ outD, ushort_t* __restrict__ outI, int nbD)
{
  const int wave = threadIdx.x >> 6, lane = threadIdx.x & 63;
  const int c0 = 2 * lane;                // 64 lanes x 2 cols = 128
  const bool isD = blockIdx.x < (unsigned)nbD;
  const int d = (isD ? blockIdx.x : blockIdx.x - nbD) * 4 + wave;
  const int Nd = isD ? NDRUG : NDIS;
  if (d >= Nd) return;
  const int nr = isD ? 3 : 4;
  float acc0 = 0.f, acc1 = 0.f;

  #pragma unroll
  for (int q = 0; q < 4; ++q) {
    if (q >= nr) break;
    const PvRel R = isD ? P.dr[q] : P.di[q];
    const int beg = rowptr[R.rowptr_off + d];
    const int end = rowptr[R.rowptr_off + d + 1];
    if (beg == end) continue;
    const ushort_t* hsb = R.hs + R.hoff + c0;
    const int hst = R.hst;
    for (int c = beg; c < end; c += 4) {
      float cf[4]; int si[4];
      #pragma unroll
      for (int j = 0; j < 4; ++j) {
        int idx = (c + j < end) ? c + j : end - 1;
        float2 pk = pack[idx];
        cf[j] = (c + j < end) ? pk.x : 0.f;
        si[j] = __float_as_int(pk.y);
      }
      ushort2 hv[4];
      #pragma unroll
      for (int j = 0; j < 4; ++j)
        hv[j] = *reinterpret_cast<const ushort2*>(hsb + (size_t)si[j] * hst);
      #pragma unroll
      for (int j = 0; j < 4; ++j) {
        acc0 += cf[j] * bf2f(hv[j].x);
        acc1 += cf[j] * bf2f(hv[j].y);
      }
    }
  }

  float b0 = 0.f, b1 = 0.f;
  #pragma unroll
  for (int q = 0; q < 4; ++q) {
    if (q >= nr) break;
    const PvRel R = isD ? P.dr[q] : P.di[q];
    const float2 bv = *reinterpret_cast<const float2*>(&bias[R.rel * HID + c0]);
    b0 += bv.x; b1 += bv.y;
  }
  acc0 += b0; acc1 += b1;
  if (RELU) { acc0 = fmaxf(acc0, 0.f); acc1 = fmaxf(acc1, 0.f); }
  ushort2 o; o.x = f2bf(acc0); o.y = f2bf(acc1);
  ushort_t* out = isD ? outD : outI;
  *reinterpret_cast<ushort2*>(out + (size_t)d * HID + c0) = o;
}

// ================= host =================
static const int DSTh[NREL] = {1, 0, 1, 0, 1, 1, 0};

struct WsPlan {
  ushort_t *xdb1, *xib1, *xd1b, *xi1b, *xd2b, *xi2b;
  ushort_t *hs_d, *hs_i, *wcatT_d, *wcatT_i, *wfinT_d, *wfinT_i;
  float2* pack;
  float *alphaB, *wv;
  int *counts, *rowptr, *cursor, *colsrc, *bsum;
  size_t total_bytes;
};

static WsPlan plan_ws(void* d_ws) {
  WsPlan p;
  ushort_t* s = (ushort_t*)d_ws;
  p.xdb1 = s;     s += (size_t)NDRUG * 256;
  p.xib1 = s;     s += (size_t)NDIS * 256;
  p.xd1b = s;     s += (size_t)NDRUG * HID;
  p.xi1b = s;     s += (size_t)NDIS * HID;
  p.hs_d = s;     s += (size_t)NDRUG * 384;
  p.hs_i = s;     s += (size_t)NDIS * 512;
  p.wcatT_d = s;  s += 384 * 256;
  p.wcatT_i = s;  s += 512 * 256;
  p.wfinT_d = s;  s += 128 * 128;
  p.wfinT_i = s;  s += 128 * 128;
  p.xd2b = p.xdb1;   // alias: xdb1 dead after L1 GEMM/alpha
  p.xi2b = p.xib1;
  p.pack = (float2*)s;   // ushort count above is even -> 8B aligned
  float2* e = p.pack + (size_t)NREL * NE;
  float* f = (float*)e;
  p.alphaB = f;   f += (size_t)15 * NDIS;   // 14 rows + 1 dummy
  p.wv = f;       f += 14 * 256;
  int* q = (int*)f;
  p.counts = q;   q += NS_TOT;
  p.rowptr = q;   q += NS_TOT;
  p.cursor = q;   q += NS_TOT;
  p.colsrc = q;   q += NREL * NE;
  p.bsum = q;     q += 512;
  p.total_bytes = (size_t)((char*)q - (char*)d_ws);
  return p;
}

static void run_layer(const ushort_t* XDb, const ushort_t* XIb, int K,
                      const float* Wsrc, const float* Wdst,
                      const float* as_, const float* ad_, const float* bias,
                      ushort_t* outDb, ushort_t* outIb, bool relu,
                      const WsPlan& p, hipStream_t stream)
{
  int4 rd = make_int4(0, 2, 6, 0);
  int4 ri4 = make_int4(1, 3, 4, 5);
  build_wcat2<<<(K * 896 + 255) / 256, 256, 0, stream>>>(
      Wsrc, p.wcatT_d, 384, rd, Wsrc, p.wcatT_i, 512, ri4, K);
  wvec_kernel<<<dim3(14, K / 4), 256, 0, stream>>>(Wsrc, as_, Wdst, ad_, p.wv, K);

  AlphaJobs jd = {};
  jd.wslot[0] = 0;     jd.outOff[0] = 0 * NDIS;
  jd.wslot[1] = 2;     jd.outOff[1] = 2 * NDIS;
  jd.wslot[2] = 6;     jd.outOff[2] = 6 * NDIS;
  jd.wslot[3] = 7 + 1; jd.outOff[3] = (7 + 1) * NDIS;
  jd.wslot[4] = 7 + 3; jd.outOff[4] = (7 + 3) * NDIS;
  jd.wslot[5] = 7 + 6; jd.outOff[5] = (7 + 6) * NDIS;
  jd.wslot[6] = 0;     jd.outOff[6] = 14 * NDIS;   // dummy
  jd.wslot[7] = 0;     jd.outOff[7] = 14 * NDIS;   // dummy
  AlphaJobs ji = {};
  ji.wslot[0] = 1;     ji.outOff[0] = 1 * NDIS;
  ji.wslot[1] = 3;     ji.outOff[1] = 3 * NDIS;
  ji.wslot[2] = 4;     ji.outOff[2] = 4 * NDIS;
  ji.wslot[3] = 5;     ji.outOff[3] = 5 * NDIS;
  ji.wslot[4] = 7 + 0; ji.outOff[4] = (7 + 0) * NDIS;
  ji.wslot[5] = 7 + 2; ji.outOff[5] = (7 + 2) * NDIS;
  ji.wslot[6] = 7 + 4; ji.outOff[6] = (7 + 4) * NDIS;
  ji.wslot[7] = 7 + 5; ji.outOff[7] = (7 + 5) * NDIS;
  int gbD = (NDRUG + 255) / 256, gbI = (NDIS + 255) / 256;
  if (K == 256)
    alpha_dual<256><<<gbD + gbI, 256, 0, stream>>>(XDb, XIb, p.wv, p.alphaB, jd, ji, gbD);
  else
    alpha_dual<128><<<gbD + gbI, 256, 0, stream>>>(XDb, XIb, p.wv, p.alphaB, jd, ji, gbD);

  // hs GEMMs (both node types, one dispatch; 128x256 tiles)
  GemmJob g0 = {XDb, p.wcatT_d, nullptr, p.hs_d, NDRUG, 384};
  GemmJob g1 = {XIb, p.wcatT_i, nullptr, p.hs_i, NDIS, 512};
  int gx0 = (NDRUG + 127) / 128, gx1 = (NDIS + 127) / 128;
  gemm_dual<false, false, true><<<dim3(gx0 + gx1, 2), 256, 0, stream>>>(g0, g1, gx0, K);

  // softmax coefs -> pack (normalized)
  NdArr nds;
  for (int r = 0; r < NREL; ++r) nds.nd[r] = DSTh[r] == 0 ? NDRUG : NDIS;
  coef_k<<<dim3((NDIS + 255) / 256, NREL), 256, 0, stream>>>(
      p.rowptr, p.colsrc, p.pack, p.alphaB, nds);

  // PV gather
  PvParams P;
  P.dr[0] = {1, 1 * RPSTR, p.hs_i, 512, 0};
  P.dr[1] = {3, 3 * RPSTR, p.hs_i, 512, 128};
  P.dr[2] = {6, 6 * RPSTR, p.hs_d, 384, 256};
  P.di[0] = {0, 0 * RPSTR, p.hs_d, 384, 0};
  P.di[1] = {2, 2 * RPSTR, p.hs_d, 384, 128};
  P.di[2] = {4, 4 * RPSTR, p.hs_i, 512, 256};
  P.di[3] = {5, 5 * RPSTR, p.hs_i, 512, 384};
  int nbD = (NDRUG + 3) / 4, nbI = (NDIS + 3) / 4;
  if (relu)
    pv_multi<true><<<nbD + nbI, 256, 0, stream>>>(
        P, p.rowptr, p.pack, bias, outDb, outIb, nbD);
  else
    pv_multi<false><<<nbD + nbI, 256, 0, stream>>>(
        P, p.rowptr, p.pack, bias, outDb, outIb, nbD);
}

extern "C" void kernel_launch(void* const* d_in, const int* in_sizes, int n_in,
                              void* d_out, int out_size, void* d_ws, size_t ws_size,
                              hipStream_t stream) {
  const float* x_drug = (const float*)d_in[0];
  const float* x_dis  = (const float*)d_in[1];
  RelIdx ri;
  for (int r = 0; r < NREL; ++r) {
    const int* e = (const int*)d_in[2 + r];
    ri.src[r] = e; ri.dst[r] = e + NE;
  }
  const float* W1s = (const float*)d_in[9];
  const float* W1d = (const float*)d_in[10];
  const float* a1s = (const float*)d_in[11];
  const float* a1d = (const float*)d_in[12];
  const float* b1  = (const float*)d_in[13];
  const float* W2s = (const float*)d_in[14];
  const float* W2d = (const float*)d_in[15];
  const float* a2s = (const float*)d_in[16];
  const float* a2d = (const float*)d_in[17];
  const float* b2  = (const float*)d_in[18];
  const float* Wdr = (const float*)d_in[19];
  const float* bdr = (const float*)d_in[20];
  const float* Wdi = (const float*)d_in[21];
  const float* bdi = (const float*)d_in[22];

  WsPlan p = plan_ws(d_ws);
  if (p.total_bytes > ws_size) return;

  cvt2_f32_bf16<<<((NDRUG + NDIS) * 256 / 8 + 255) / 256, 256, 0, stream>>>(
      x_drug, p.xdb1, NDRUG * 256 / 8, x_dis, p.xib1, NDIS * 256 / 8);

  // CSR build (reused by both layers)
  zero_ints<<<(NS_TOT + 255) / 256, 256, 0, stream>>>(p.counts, NS_TOT);
  dim3 ge((NE + 255) / 256, NREL);
  hist_k<<<ge, 256, 0, stream>>>(ri, p.counts);
  int nb = (NS_TOT + 1023) / 1024;
  scan_blk<<<nb, 256, 0, stream>>>(p.counts, p.cursor, p.bsum, NS_TOT);
  scan_fin<<<nb, 512, 0, stream>>>(p.cursor, p.bsum, p.rowptr, p.cursor, NS_TOT);
  fill_k<<<ge, 256, 0, stream>>>(ri, p.cursor, p.colsrc);

  // Layer 1 (K=256, relu), Layer 2 (K=128)
  run_layer(p.xdb1, p.xib1, 256, W1s, W1d, a1s, a1d, b1, p.xd1b, p.xi1b, true, p, stream);
  run_layer(p.xd1b, p.xi1b, 128, W2s, W2d, a2s, a2d, b2, p.xd2b, p.xi2b, false, p, stream);

  // final linear + bias + relu -> d_out (f32)
  int4 r0 = make_int4(0, 0, 0, 0);
  build_wcat2<<<(128 * 128 * 2 + 255) / 256, 256, 0, stream>>>(
      Wdr, p.wfinT_d, 128, r0, Wdi, p.wfinT_i, 128, r0, 128);
  float* out = (float*)d_out;
  GemmJob f0 = {p.xd2b, p.wfinT_d, bdr, out, NDRUG, 128};
  GemmJob f1 = {p.xi2b, p.wfinT_i, bdi, out + (size_t)NDRUG * HID, NDIS, 128};
  int gx0 = (NDRUG + 127) / 128, gx1 = (NDIS + 127) / 128;
  gemm_dual<true, true, false><<<dim3(gx0 + gx1, 1), 256, 0, stream>>>(f0, f1, gx0, 128);
}

// Round 9
// 479.176 us; speedup vs baseline: 1.1709x; 1.1709x over previous
//
#include <hip/hip_runtime.h>
#include <stdint.h>

#define NDRUG 20000
#define NDIS  40000
#define HID   128
#define NE    150000
#define NREL  7
#define RPSTR (NDIS + 1)
#define NS_TOT (NREL * RPSTR)

typedef unsigned short ushort_t;
typedef __attribute__((ext_vector_type(8))) short bf16x8;
typedef __attribute__((ext_vector_type(4))) float f32x4;
typedef const __attribute__((address_space(1))) void gv_t;
typedef __attribute__((address_space(3))) void lv_t;

__device__ __forceinline__ ushort_t f2bf(float f) {
  unsigned u = __float_as_uint(f);
  u += 0x7FFFu + ((u >> 16) & 1u);          // RNE
  return (ushort_t)(u >> 16);
}
__device__ __forceinline__ float bf2f(ushort_t h) {
  return __uint_as_float(((unsigned)h) << 16);
}

// ============ dual-job bf16 MFMA GEMM: C = A[M,K] @ BT[N,K]^T ============
// 128x128 tile (measured-best at this structure), 4 waves, global_load_lds 16B.
struct GemmJob { const ushort_t* A; const ushort_t* BT; const float* bias; void* C; int M, N; };

template<bool BIAS, bool RELU, bool BF16OUT>
__global__ __launch_bounds__(256) void gemm_dual(GemmJob j0, GemmJob j1, int gx0, int K)
{
  __shared__ ushort_t As[128 * 32];
  __shared__ ushort_t Bs[128 * 32];
  const bool first = blockIdx.x < (unsigned)gx0;
  const GemmJob J = first ? j0 : j1;
  const int bx = first ? blockIdx.x : blockIdx.x - gx0;
  if ((int)blockIdx.y * 128 >= J.N) return;   // uniform exit, before any sync
  const int tid = threadIdx.x;
  const int m0 = bx * 128;
  const int n0 = blockIdx.y * 128;
  const int wave = tid >> 6, lane = tid & 63;
  const int wm = wave & 1, wn = wave >> 1;
  const int l15 = lane & 15, lk = lane >> 4;

  const int rowS = wave * 16 + (lane >> 2);
  const int chunk = (lane & 3) * 8;
  const ushort_t* ga0 = J.A + (size_t)min(m0 + rowS, J.M - 1) * K + chunk;
  const ushort_t* ga1 = J.A + (size_t)min(m0 + rowS + 64, J.M - 1) * K + chunk;
  const ushort_t* gb0 = J.BT + (size_t)(n0 + rowS) * K + chunk;
  const ushort_t* gb1 = J.BT + (size_t)(n0 + rowS + 64) * K + chunk;

  f32x4 acc[4][4] = {};

  for (int k0 = 0; k0 < K; k0 += 32) {
    __syncthreads();
    __builtin_amdgcn_global_load_lds((gv_t*)(ga0 + k0), (lv_t*)(As + wave * 512), 16, 0, 0);
    __builtin_amdgcn_global_load_lds((gv_t*)(ga1 + k0), (lv_t*)(As + wave * 512 + 2048), 16, 0, 0);
    __builtin_amdgcn_global_load_lds((gv_t*)(gb0 + k0), (lv_t*)(Bs + wave * 512), 16, 0, 0);
    __builtin_amdgcn_global_load_lds((gv_t*)(gb1 + k0), (lv_t*)(Bs + wave * 512 + 2048), 16, 0, 0);
    __syncthreads();

    bf16x8 af[4], bfg[4];
    #pragma unroll
    for (int m = 0; m < 4; ++m)
      af[m] = *reinterpret_cast<const bf16x8*>(&As[(wm * 64 + m * 16 + l15) * 32 + lk * 8]);
    #pragma unroll
    for (int n = 0; n < 4; ++n)
      bfg[n] = *reinterpret_cast<const bf16x8*>(&Bs[(wn * 64 + n * 16 + l15) * 32 + lk * 8]);
    #pragma unroll
    for (int m = 0; m < 4; ++m)
      #pragma unroll
      for (int n = 0; n < 4; ++n)
        acc[m][n] = __builtin_amdgcn_mfma_f32_16x16x32_bf16(af[m], bfg[n], acc[m][n], 0, 0, 0);
  }

  #pragma unroll
  for (int m = 0; m < 4; ++m) {
    int rbase = m0 + wm * 64 + m * 16 + lk * 4;
    #pragma unroll
    for (int n = 0; n < 4; ++n) {
      int col = n0 + wn * 64 + n * 16 + l15;
      float bv = 0.f;
      if (BIAS) bv = J.bias[col];
      #pragma unroll
      for (int j = 0; j < 4; ++j) {
        int row = rbase + j;
        if (row >= J.M) continue;
        float v = acc[m][n][j] + bv;
        if (RELU) v = fmaxf(v, 0.f);
        if (BF16OUT) ((ushort_t*)J.C)[(size_t)row * J.N + col] = f2bf(v);
        else         ((float*)J.C)[(size_t)row * J.N + col] = v;
      }
    }
  }
}

// ================= weight prep (two outputs in one dispatch) =================
__global__ void build_wcat2(const float* __restrict__ WA, ushort_t* __restrict__ outA,
                            int ncolA, int4 relsA,
                            const float* __restrict__ WB, ushort_t* __restrict__ outB,
                            int ncolB, int4 relsB, int K)
{
  int id = blockIdx.x * 256 + threadIdx.x;
  const float* W; ushort_t* out; int ncol; int4 rels;
  int totA = K * ncolA;
  if (id < totA) { W = WA; out = outA; ncol = ncolA; rels = relsA; }
  else {
    id -= totA;
    if (id >= K * ncolB) return;
    W = WB; out = outB; ncol = ncolB; rels = relsB;
  }
  int k = id / ncol, c = id - k * ncol;
  int rr = (&rels.x)[c >> 7];
  out[(size_t)c * K + k] = f2bf(W[((size_t)rr * K + k) * HID + (c & 127)]);
}

// wv[slot][k] = sum_j W[r][k][j] * a[r][j]   (slot<7: src, else dst)
__global__ __launch_bounds__(256) void wvec_kernel(
    const float* __restrict__ Wsrc, const float* __restrict__ as_,
    const float* __restrict__ Wdst, const float* __restrict__ ad_,
    float* __restrict__ wv, int K)
{
  int slot = blockIdx.x;
  int r = slot % NREL;
  const float* W = (slot < NREL ? Wsrc : Wdst) + (size_t)r * K * HID;
  const float* a = (slot < NREL ? as_ : ad_) + r * HID;
  int wave = threadIdx.x >> 6, lane = threadIdx.x & 63;
  int k = blockIdx.y * 4 + wave;
  if (k >= K) return;
  float s = W[(size_t)k * HID + lane] * a[lane]
          + W[(size_t)k * HID + 64 + lane] * a[64 + lane];
  #pragma unroll
  for (int off = 32; off; off >>= 1) s += __shfl_xor(s, off);
  if (lane == 0) wv[slot * 256 + k] = s;
}

// ================= f32 -> bf16 convert (two tensors, one dispatch) =================
__global__ void cvt2_f32_bf16(const float* __restrict__ inA, ushort_t* __restrict__ outA, int n8A,
                              const float* __restrict__ inB, ushort_t* __restrict__ outB, int n8B)
{
  int i = blockIdx.x * 256 + threadIdx.x;
  const float* in; ushort_t* out;
  if (i < n8A) { in = inA; out = outA; }
  else {
    i -= n8A;
    if (i >= n8B) return;
    in = inB; out = outB;
  }
  float4 a = reinterpret_cast<const float4*>(in)[2 * i];
  float4 b = reinterpret_cast<const float4*>(in)[2 * i + 1];
  ushort_t r[8] = {f2bf(a.x), f2bf(a.y), f2bf(a.z), f2bf(a.w),
                   f2bf(b.x), f2bf(b.y), f2bf(b.z), f2bf(b.w)};
  reinterpret_cast<uint4*>(out)[i] = *reinterpret_cast<uint4*>(r);
}

// ================= batched alpha GEMV, both node types in one dispatch =================
struct AlphaJobs { int wslot[8]; int outOff[8]; };

template<int K>
__global__ __launch_bounds__(256) void alpha_dual(
    const ushort_t* __restrict__ XD, const ushort_t* __restrict__ XI,
    const float* __restrict__ wv, float* __restrict__ outBase,
    AlphaJobs jd, AlphaJobs ji, int gbD)
{
  const bool isD = blockIdx.x < (unsigned)gbD;
  const ushort_t* X = isD ? XD : XI;
  const int N = isD ? NDRUG : NDIS;
  const AlphaJobs jobs = isD ? jd : ji;
  int i = (isD ? blockIdx.x : blockIdx.x - gbD) * 256 + threadIdx.x;
  if (i >= N) return;
  float acc[8];
  #pragma unroll
  for (int v = 0; v < 8; ++v) acc[v] = 0.f;
  const ushort_t* xp = X + (size_t)i * K;
  for (int k = 0; k < K; k += 8) {
    uint4 u = *reinterpret_cast<const uint4*>(xp + k);
    unsigned uu[4] = {u.x, u.y, u.z, u.w};
    float xf[8];
    #pragma unroll
    for (int q = 0; q < 4; ++q) {
      xf[2 * q]     = __uint_as_float(uu[q] << 16);
      xf[2 * q + 1] = __uint_as_float(uu[q] & 0xFFFF0000u);
    }
    #pragma unroll
    for (int v = 0; v < 8; ++v) {
      const float* wp = wv + jobs.wslot[v] * 256 + k;
      #pragma unroll
      for (int q = 0; q < 8; ++q) acc[v] += xf[q] * wp[q];
    }
  }
  #pragma unroll
  for (int v = 0; v < 8; ++v) outBase[jobs.outOff[v] + i] = acc[v];
}

// ================= CSR build =================
struct RelIdx { const int* src[NREL]; const int* dst[NREL]; };
struct NdArr  { int nd[NREL]; };

__global__ void zero_ints(int* __restrict__ p, int n) {
  int i = blockIdx.x * 256 + threadIdx.x;
  if (i < n) p[i] = 0;
}
__global__ void hist_k(RelIdx ri, int* __restrict__ counts) {
  int e = blockIdx.x * 256 + threadIdx.x;
  int r = blockIdx.y;
  if (e >= NE) return;
  atomicAdd(&counts[r * RPSTR + ri.dst[r][e]], 1);
}
__global__ __launch_bounds__(256) void scan_blk(const int* __restrict__ in,
                                                int* __restrict__ partial,
                                                int* __restrict__ bsum, int n)
{
  __shared__ int ts[256];
  int t = threadIdx.x;
  int base = blockIdx.x * 1024 + t * 4;
  int v[4];
  #pragma unroll
  for (int i = 0; i < 4; ++i) v[i] = (base + i < n) ? in[base + i] : 0;
  int s = v[0] + v[1] + v[2] + v[3];
  ts[t] = s; __syncthreads();
  for (int off = 1; off < 256; off <<= 1) {
    int x = (t >= off) ? ts[t - off] : 0;
    __syncthreads();
    ts[t] += x;
    __syncthreads();
  }
  int run = ts[t] - s;
  #pragma unroll
  for (int i = 0; i < 4; ++i) {
    if (base + i < n) partial[base + i] = run;
    run += v[i];
  }
  if (t == 255) bsum[blockIdx.x] = ts[255];
}
// block bx: rowptr/cursor[bx*1024 + i] = partial[...] + sum(bsum[0..bx))
__global__ __launch_bounds__(512) void scan_fin(const int* __restrict__ partial,
                                                const int* __restrict__ bsum,
                                                int* __restrict__ rowptr,
                                                int* __restrict__ cursor, int n)
{
  __shared__ int ts[512];
  int t = threadIdx.x;
  ts[t] = (t < (int)blockIdx.x) ? bsum[t] : 0;   // nb <= 512
  __syncthreads();
  #pragma unroll
  for (int off = 256; off; off >>= 1) {
    if (t < off) ts[t] += ts[t + off];
    __syncthreads();
  }
  int base = ts[0];
  #pragma unroll
  for (int i = 0; i < 2; ++i) {
    int idx = blockIdx.x * 1024 + t + i * 512;
    if (idx < n) {
      int v = partial[idx] + base;
      rowptr[idx] = v; cursor[idx] = v;
    }
  }
}
__global__ void fill_k(RelIdx ri, int* __restrict__ cursor, int* __restrict__ colsrc) {
  int e = blockIdx.x * 256 + threadIdx.x;
  int r = blockIdx.y;
  if (e >= NE) return;
  int d = ri.dst[r][e];
  int pos = atomicAdd(&cursor[r * RPSTR + d], 1);
  colsrc[pos] = ri.src[r][e];
}

// ==== per-(rel,dst) softmax: coef[i] = exp(a-m); invden[rel][d] stored ====
__global__ __launch_bounds__(256) void coef_k(
    const int* __restrict__ rowptr, const int* __restrict__ colsrc,
    float* __restrict__ coef, const float* __restrict__ alphaB,
    float* __restrict__ invden, NdArr nds)
{
  int d = blockIdx.x * 256 + threadIdx.x;
  int r = blockIdx.y;
  if (d >= nds.nd[r]) return;
  int beg = rowptr[r * RPSTR + d], end = rowptr[r * RPSTR + d + 1];
  if (beg == end) return;
  const float ad = alphaB[(NREL + r) * NDIS + d];
  const float* as = alphaB + (size_t)r * NDIS;
  int deg = end - beg;
  float sum = 0.f;
  if (deg <= 16) {
    float av[16];
    float m = -1e30f;
    #pragma unroll
    for (int i = 0; i < 16; ++i) {
      float a = -1e30f;
      if (i < deg) {
        int s = colsrc[beg + i];
        a = as[s] + ad;
        a = a > 0.f ? a : 0.2f * a;
      }
      av[i] = a;
      m = fmaxf(m, a);
    }
    #pragma unroll
    for (int i = 0; i < 16; ++i) {
      if (i < deg) {
        float ex = __expf(av[i] - m);
        coef[beg + i] = ex;
        sum += ex;
      }
    }
  } else {
    float m = -1e30f;
    for (int i = beg; i < end; ++i) {
      float a = as[colsrc[i]] + ad;
      a = a > 0.f ? a : 0.2f * a;
      m = fmaxf(m, a);
    }
    for (int i = beg; i < end; ++i) {
      float a = as[colsrc[i]] + ad;
      a = a > 0.f ? a : 0.2f * a;
      float ex = __expf(a - m);
      coef[i] = ex;
      sum += ex;
    }
  }
  invden[r * NDIS + d] = 1.f / (sum + 1e-16f);
}

// ==== PV gather (exact r4 measured-best): full wave/dst, 2 cols/lane, 4-edge unroll ====
struct PvRel { int rel; int rowptr_off; const ushort_t* hs; int hst; int hoff; };
struct PvParams { PvRel dr[3]; PvRel di[4]; };

template<bool RELU>
__global__ __launch_bounds__(256) void pv_multi(
    PvParams P, const int* __restrict__ rowptr, const int* __restrict__ colsrc,
    const float* __restrict__ coef, const float* __restrict__ invden,
    const float* __restrict__ bias,
    ushort_t* __restrict__ outD, ushort_t* __restrict__ outI, int nbD)
{
  const int wave = threadIdx.x >> 6, lane = threadIdx.x & 63;
  const int c0 = 2 * lane;
  const bool isD = blockIdx.x < (unsigned)nbD;
  const int d = (isD ? blockIdx.x : blockIdx.x - nbD) * 4 + wave;
  const int Nd = isD ? NDRUG : NDIS;
  if (d >= Nd) return;
  const int nr = isD ? 3 : 4;
  float acc0 = 0.f, acc1 = 0.f;

  #pragma unroll
  for (int q = 0; q < 4; ++q) {
    if (q >= nr) break;
    const PvRel R = isD ? P.dr[q] : P.di[q];
    acc0 += bias[R.rel * HID + c0];
    acc1 += bias[R.rel * HID + c0 + 1];
    const int beg = rowptr[R.rowptr_off + d];
    const int end = rowptr[R.rowptr_off + d + 1];
    if (beg == end) continue;
    const ushort_t* hsb = R.hs + R.hoff + c0;
    const int hst = R.hst;
    float p0 = 0.f, p1 = 0.f;
    for (int c = beg; c < end; c += 4) {
      float cf[4]; int si[4];
      #pragma unroll
      for (int j = 0; j < 4; ++j) {
        int idx = (c + j < end) ? c + j : end - 1;
        cf[j] = (c + j < end) ? coef[idx] : 0.f;
        si[j] = colsrc[idx];
      }
      ushort2 hv[4];
      #pragma unroll
      for (int j = 0; j < 4; ++j)
        hv[j] = *reinterpret_cast<const ushort2*>(hsb + (size_t)si[j] * hst);
      #pragma unroll
      for (int j = 0; j < 4; ++j) {
        p0 += cf[j] * bf2f(hv[j].x);
        p1 += cf[j] * bf2f(hv[j].y);
      }
    }
    const float inv = invden[R.rel * NDIS + d];
    acc0 += p0 * inv;
    acc1 += p1 * inv;
  }
  if (RELU) { acc0 = fmaxf(acc0, 0.f); acc1 = fmaxf(acc1, 0.f); }
  ushort2 o; o.x = f2bf(acc0); o.y = f2bf(acc1);
  ushort_t* out = isD ? outD : outI;
  *reinterpret_cast<ushort2*>(out + (size_t)d * HID + c0) = o;
}

// ================= host =================
static const int DSTh[NREL] = {1, 0, 1, 0, 1, 1, 0};

struct WsPlan {
  ushort_t *xdb1, *xib1, *xd1b, *xi1b, *xd2b, *xi2b;
  ushort_t *hs_d, *hs_i, *wcatT_d, *wcatT_i, *wfinT_d, *wfinT_i;
  float *alphaB, *wv, *coef, *invden;
  int *counts, *rowptr, *cursor, *colsrc, *bsum;
  size_t total_bytes;
};

static WsPlan plan_ws(void* d_ws) {
  WsPlan p;
  ushort_t* s = (ushort_t*)d_ws;
  p.xdb1 = s;     s += (size_t)NDRUG * 256;
  p.xib1 = s;     s += (size_t)NDIS * 256;
  p.xd1b = s;     s += (size_t)NDRUG * HID;
  p.xi1b = s;     s += (size_t)NDIS * HID;
  p.hs_d = s;     s += (size_t)NDRUG * 384;
  p.hs_i = s;     s += (size_t)NDIS * 512;
  p.wcatT_d = s;  s += 384 * 256;
  p.wcatT_i = s;  s += 512 * 256;
  p.wfinT_d = s;  s += 128 * 128;
  p.wfinT_i = s;  s += 128 * 128;
  p.xd2b = p.xdb1;   // alias: xdb1 dead after L1 GEMM/alpha
  p.xi2b = p.xib1;
  float* f = (float*)s;
  p.alphaB = f;   f += (size_t)15 * NDIS;   // 14 rows + 1 dummy
  p.wv = f;       f += 14 * 256;
  p.coef = f;     f += (size_t)NREL * NE;
  p.invden = f;   f += (size_t)NREL * NDIS;
  int* q = (int*)f;
  p.counts = q;   q += NS_TOT;
  p.rowptr = q;   q += NS_TOT;
  p.cursor = q;   q += NS_TOT;
  p.colsrc = q;   q += NREL * NE;
  p.bsum = q;     q += 512;
  p.total_bytes = (size_t)((char*)q - (char*)d_ws);
  return p;
}

static void run_layer(const ushort_t* XDb, const ushort_t* XIb, int K,
                      const float* Wsrc, const float* Wdst,
                      const float* as_, const float* ad_, const float* bias,
                      ushort_t* outDb, ushort_t* outIb, bool relu,
                      const WsPlan& p, hipStream_t stream)
{
  int4 rd = make_int4(0, 2, 6, 0);
  int4 ri4 = make_int4(1, 3, 4, 5);
  build_wcat2<<<(K * 896 + 255) / 256, 256, 0, stream>>>(
      Wsrc, p.wcatT_d, 384, rd, Wsrc, p.wcatT_i, 512, ri4, K);
  wvec_kernel<<<dim3(14, K / 4), 256, 0, stream>>>(Wsrc, as_, Wdst, ad_, p.wv, K);

  AlphaJobs jd = {};
  jd.wslot[0] = 0;     jd.outOff[0] = 0 * NDIS;
  jd.wslot[1] = 2;     jd.outOff[1] = 2 * NDIS;
  jd.wslot[2] = 6;     jd.outOff[2] = 6 * NDIS;
  jd.wslot[3] = 7 + 1; jd.outOff[3] = (7 + 1) * NDIS;
  jd.wslot[4] = 7 + 3; jd.outOff[4] = (7 + 3) * NDIS;
  jd.wslot[5] = 7 + 6; jd.outOff[5] = (7 + 6) * NDIS;
  jd.wslot[6] = 0;     jd.outOff[6] = 14 * NDIS;   // dummy
  jd.wslot[7] = 0;     jd.outOff[7] = 14 * NDIS;   // dummy
  AlphaJobs ji = {};
  ji.wslot[0] = 1;     ji.outOff[0] = 1 * NDIS;
  ji.wslot[1] = 3;     ji.outOff[1] = 3 * NDIS;
  ji.wslot[2] = 4;     ji.outOff[2] = 4 * NDIS;
  ji.wslot[3] = 5;     ji.outOff[3] = 5 * NDIS;
  ji.wslot[4] = 7 + 0; ji.outOff[4] = (7 + 0) * NDIS;
  ji.wslot[5] = 7 + 2; ji.outOff[5] = (7 + 2) * NDIS;
  ji.wslot[6] = 7 + 4; ji.outOff[6] = (7 + 4) * NDIS;
  ji.wslot[7] = 7 + 5; ji.outOff[7] = (7 + 5) * NDIS;
  int gbD = (NDRUG + 255) / 256, gbI = (NDIS + 255) / 256;
  if (K == 256)
    alpha_dual<256><<<gbD + gbI, 256, 0, stream>>>(XDb, XIb, p.wv, p.alphaB, jd, ji, gbD);
  else
    alpha_dual<128><<<gbD + gbI, 256, 0, stream>>>(XDb, XIb, p.wv, p.alphaB, jd, ji, gbD);

  // hs GEMMs (both node types, one dispatch; 128x128 tiles)
  GemmJob g0 = {XDb, p.wcatT_d, nullptr, p.hs_d, NDRUG, 384};
  GemmJob g1 = {XIb, p.wcatT_i, nullptr, p.hs_i, NDIS, 512};
  int gx0 = (NDRUG + 127) / 128, gx1 = (NDIS + 127) / 128;
  gemm_dual<false, false, true><<<dim3(gx0 + gx1, 4), 256, 0, stream>>>(g0, g1, gx0, K);

  // softmax coefs
  NdArr nds;
  for (int r = 0; r < NREL; ++r) nds.nd[r] = DSTh[r] == 0 ? NDRUG : NDIS;
  coef_k<<<dim3((NDIS + 255) / 256, NREL), 256, 0, stream>>>(
      p.rowptr, p.colsrc, p.coef, p.alphaB, p.invden, nds);

  // PV gather
  PvParams P;
  P.dr[0] = {1, 1 * RPSTR, p.hs_i, 512, 0};
  P.dr[1] = {3, 3 * RPSTR, p.hs_i, 512, 128};
  P.dr[2] = {6, 6 * RPSTR, p.hs_d, 384, 256};
  P.di[0] = {0, 0 * RPSTR, p.hs_d, 384, 0};
  P.di[1] = {2, 2 * RPSTR, p.hs_d, 384, 128};
  P.di[2] = {4, 4 * RPSTR, p.hs_i, 512, 256};
  P.di[3] = {5, 5 * RPSTR, p.hs_i, 512, 384};
  int nbD = (NDRUG + 3) / 4, nbI = (NDIS + 3) / 4;
  if (relu)
    pv_multi<true><<<nbD + nbI, 256, 0, stream>>>(
        P, p.rowptr, p.colsrc, p.coef, p.invden, bias, outDb, outIb, nbD);
  else
    pv_multi<false><<<nbD + nbI, 256, 0, stream>>>(
        P, p.rowptr, p.colsrc, p.coef, p.invden, bias, outDb, outIb, nbD);
}

extern "C" void kernel_launch(void* const* d_in, const int* in_sizes, int n_in,
                              void* d_out, int out_size, void* d_ws, size_t ws_size,
                              hipStream_t stream) {
  const float* x_drug = (const float*)d_in[0];
  const float* x_dis  = (const float*)d_in[1];
  RelIdx ri;
  for (int r = 0; r < NREL; ++r) {
    const int* e = (const int*)d_in[2 + r];
    ri.src[r] = e; ri.dst[r] = e + NE;
  }
  const float* W1s = (const float*)d_in[9];
  const float* W1d = (const float*)d_in[10];
  const float* a1s = (const float*)d_in[11];
  const float* a1d = (const float*)d_in[12];
  const float* b1  = (const float*)d_in[13];
  const float* W2s = (const float*)d_in[14];
  const float* W2d = (const float*)d_in[15];
  const float* a2s = (const float*)d_in[16];
  const float* a2d = (const float*)d_in[17];
  const float* b2  = (const float*)d_in[18];
  const float* Wdr = (const float*)d_in[19];
  const float* bdr = (const float*)d_in[20];
  const float* Wdi = (const float*)d_in[21];
  const float* bdi = (const float*)d_in[22];

  WsPlan p = plan_ws(d_ws);
  if (p.total_bytes > ws_size) return;

  cvt2_f32_bf16<<<((NDRUG + NDIS) * 256 / 8 + 255) / 256, 256, 0, stream>>>(
      x_drug, p.xdb1, NDRUG * 256 / 8, x_dis, p.xib1, NDIS * 256 / 8);

  // CSR build (reused by both layers)
  zero_ints<<<(NS_TOT + 255) / 256, 256, 0, stream>>>(p.counts, NS_TOT);
  dim3 ge((NE + 255) / 256, NREL);
  hist_k<<<ge, 256, 0, stream>>>(ri, p.counts);
  int nb = (NS_TOT + 1023) / 1024;
  scan_blk<<<nb, 256, 0, stream>>>(p.counts, p.cursor, p.bsum, NS_TOT);
  scan_fin<<<nb, 512, 0, stream>>>(p.cursor, p.bsum, p.rowptr, p.cursor, NS_TOT);
  fill_k<<<ge, 256, 0, stream>>>(ri, p.cursor, p.colsrc);

  // Layer 1 (K=256, relu), Layer 2 (K=128)
  run_layer(p.xdb1, p.xib1, 256, W1s, W1d, a1s, a1d, b1, p.xd1b, p.xi1b, true, p, stream);
  run_layer(p.xd1b, p.xi1b, 128, W2s, W2d, a2s, a2d, b2, p.xd2b, p.xi2b, false, p, stream);

  // final linear + bias + relu -> d_out (f32)
  int4 r0 = make_int4(0, 0, 0, 0);
  build_wcat2<<<(128 * 128 * 2 + 255) / 256, 256, 0, stream>>>(
      Wdr, p.wfinT_d, 128, r0, Wdi, p.wfinT_i, 128, r0, 128);
  float* out = (float*)d_out;
  GemmJob f0 = {p.xd2b, p.wfinT_d, bdr, out, NDRUG, 128};
  GemmJob f1 = {p.xi2b, p.wfinT_i, bdi, out + (size_t)NDRUG * HID, NDIS, 128};
  int gx0 = (NDRUG + 127) / 128, gx1 = (NDIS + 127) / 128;
  gemm_dual<true, true, false><<<dim3(gx0 + gx1, 1), 256, 0, stream>>>(f0, f1, gx0, 128);
}

// Round 10
// 470.642 us; speedup vs baseline: 1.1921x; 1.0181x over previous
//
#include <hip/hip_runtime.h>
#include <stdint.h>

#define NDRUG 20000
#define NDIS  40000
#define HID   128
#define NE    150000
#define NREL  7
#define RPSTR (NDIS + 1)
#define NS_TOT (NREL * RPSTR)

typedef unsigned short ushort_t;
typedef __attribute__((ext_vector_type(8))) short bf16x8;
typedef __attribute__((ext_vector_type(4))) float f32x4;
typedef const __attribute__((address_space(1))) void gv_t;
typedef __attribute__((address_space(3))) void lv_t;

__device__ __forceinline__ ushort_t f2bf(float f) {
  unsigned u = __float_as_uint(f);
  u += 0x7FFFu + ((u >> 16) & 1u);          // RNE
  return (ushort_t)(u >> 16);
}
__device__ __forceinline__ float bf2f(ushort_t h) {
  return __uint_as_float(((unsigned)h) << 16);
}

// ============ dual-job bf16 MFMA GEMM: C = A[M,K] @ BT[N,K]^T ============
// 128x128 tile, 4 waves, 2-phase prefetch: double-buffered LDS, next k-step's
// global_load_lds issued BEFORE current step's ds_read+MFMA, 1 barrier/step.
struct GemmJob { const ushort_t* A; const ushort_t* BT; const float* bias; void* C; int M, N; };

template<bool BIAS, bool RELU, bool BF16OUT>
__global__ __launch_bounds__(256) void gemm_dual(GemmJob j0, GemmJob j1, int gx0, int K)
{
  __shared__ ushort_t As[2][128 * 32];   // 2 x 8 KB
  __shared__ ushort_t Bs[2][128 * 32];
  const bool first = blockIdx.x < (unsigned)gx0;
  const GemmJob J = first ? j0 : j1;
  const int bx = first ? blockIdx.x : blockIdx.x - gx0;
  if ((int)blockIdx.y * 128 >= J.N) return;   // uniform exit, before any sync
  const int tid = threadIdx.x;
  const int m0 = bx * 128;
  const int n0 = blockIdx.y * 128;
  const int wave = tid >> 6, lane = tid & 63;
  const int wm = wave & 1, wn = wave >> 1;
  const int l15 = lane & 15, lk = lane >> 4;

  const int rowS = wave * 16 + (lane >> 2);
  const int chunk = (lane & 3) * 8;
  const ushort_t* ga0 = J.A + (size_t)min(m0 + rowS, J.M - 1) * K + chunk;
  const ushort_t* ga1 = J.A + (size_t)min(m0 + rowS + 64, J.M - 1) * K + chunk;
  const ushort_t* gb0 = J.BT + (size_t)(n0 + rowS) * K + chunk;
  const ushort_t* gb1 = J.BT + (size_t)(n0 + rowS + 64) * K + chunk;

#define GEMM_STAGE(buf, koff)                                                              \
  do {                                                                                     \
    __builtin_amdgcn_global_load_lds((gv_t*)(ga0 + (koff)), (lv_t*)(&As[buf][wave * 512]), 16, 0, 0);        \
    __builtin_amdgcn_global_load_lds((gv_t*)(ga1 + (koff)), (lv_t*)(&As[buf][wave * 512 + 2048]), 16, 0, 0); \
    __builtin_amdgcn_global_load_lds((gv_t*)(gb0 + (koff)), (lv_t*)(&Bs[buf][wave * 512]), 16, 0, 0);        \
    __builtin_amdgcn_global_load_lds((gv_t*)(gb1 + (koff)), (lv_t*)(&Bs[buf][wave * 512 + 2048]), 16, 0, 0); \
  } while (0)

  f32x4 acc[4][4] = {};
  const int nt = K >> 5;

  GEMM_STAGE(0, 0);
  __syncthreads();                       // tile 0 landed (barrier drains vmcnt)

  for (int t = 0; t < nt; ++t) {
    if (t + 1 < nt) GEMM_STAGE((t + 1) & 1, (t + 1) * 32);  // prefetch overlaps MFMA below
    const ushort_t* Ab = As[t & 1];
    const ushort_t* Bb = Bs[t & 1];
    bf16x8 af[4], bfg[4];
    #pragma unroll
    for (int m = 0; m < 4; ++m)
      af[m] = *reinterpret_cast<const bf16x8*>(&Ab[(wm * 64 + m * 16 + l15) * 32 + lk * 8]);
    #pragma unroll
    for (int n = 0; n < 4; ++n)
      bfg[n] = *reinterpret_cast<const bf16x8*>(&Bb[(wn * 64 + n * 16 + l15) * 32 + lk * 8]);
    #pragma unroll
    for (int m = 0; m < 4; ++m)
      #pragma unroll
      for (int n = 0; n < 4; ++n)
        acc[m][n] = __builtin_amdgcn_mfma_f32_16x16x32_bf16(af[m], bfg[n], acc[m][n], 0, 0, 0);
    __syncthreads();                     // drains prefetch + protects buffer reuse
  }
#undef GEMM_STAGE

  #pragma unroll
  for (int m = 0; m < 4; ++m) {
    int rbase = m0 + wm * 64 + m * 16 + lk * 4;
    #pragma unroll
    for (int n = 0; n < 4; ++n) {
      int col = n0 + wn * 64 + n * 16 + l15;
      float bv = 0.f;
      if (BIAS) bv = J.bias[col];
      #pragma unroll
      for (int j = 0; j < 4; ++j) {
        int row = rbase + j;
        if (row >= J.M) continue;
        float v = acc[m][n][j] + bv;
        if (RELU) v = fmaxf(v, 0.f);
        if (BF16OUT) ((ushort_t*)J.C)[(size_t)row * J.N + col] = f2bf(v);
        else         ((float*)J.C)[(size_t)row * J.N + col] = v;
      }
    }
  }
}

// ================= weight prep (two outputs in one dispatch) =================
__global__ void build_wcat2(const float* __restrict__ WA, ushort_t* __restrict__ outA,
                            int ncolA, int4 relsA,
                            const float* __restrict__ WB, ushort_t* __restrict__ outB,
                            int ncolB, int4 relsB, int K)
{
  int id = blockIdx.x * 256 + threadIdx.x;
  const float* W; ushort_t* out; int ncol; int4 rels;
  int totA = K * ncolA;
  if (id < totA) { W = WA; out = outA; ncol = ncolA; rels = relsA; }
  else {
    id -= totA;
    if (id >= K * ncolB) return;
    W = WB; out = outB; ncol = ncolB; rels = relsB;
  }
  int k = id / ncol, c = id - k * ncol;
  int rr = (&rels.x)[c >> 7];
  out[(size_t)c * K + k] = f2bf(W[((size_t)rr * K + k) * HID + (c & 127)]);
}

// wv[slot][k] = sum_j W[r][k][j] * a[r][j]   (slot<7: src, else dst)
__global__ __launch_bounds__(256) void wvec_kernel(
    const float* __restrict__ Wsrc, const float* __restrict__ as_,
    const float* __restrict__ Wdst, const float* __restrict__ ad_,
    float* __restrict__ wv, int K)
{
  int slot = blockIdx.x;
  int r = slot % NREL;
  const float* W = (slot < NREL ? Wsrc : Wdst) + (size_t)r * K * HID;
  const float* a = (slot < NREL ? as_ : ad_) + r * HID;
  int wave = threadIdx.x >> 6, lane = threadIdx.x & 63;
  int k = blockIdx.y * 4 + wave;
  if (k >= K) return;
  float s = W[(size_t)k * HID + lane] * a[lane]
          + W[(size_t)k * HID + 64 + lane] * a[64 + lane];
  #pragma unroll
  for (int off = 32; off; off >>= 1) s += __shfl_xor(s, off);
  if (lane == 0) wv[slot * 256 + k] = s;
}

// ================= f32 -> bf16 convert (two tensors, one dispatch) =================
__global__ void cvt2_f32_bf16(const float* __restrict__ inA, ushort_t* __restrict__ outA, int n8A,
                              const float* __restrict__ inB, ushort_t* __restrict__ outB, int n8B)
{
  int i = blockIdx.x * 256 + threadIdx.x;
  const float* in; ushort_t* out;
  if (i < n8A) { in = inA; out = outA; }
  else {
    i -= n8A;
    if (i >= n8B) return;
    in = inB; out = outB;
  }
  float4 a = reinterpret_cast<const float4*>(in)[2 * i];
  float4 b = reinterpret_cast<const float4*>(in)[2 * i + 1];
  ushort_t r[8] = {f2bf(a.x), f2bf(a.y), f2bf(a.z), f2bf(a.w),
                   f2bf(b.x), f2bf(b.y), f2bf(b.z), f2bf(b.w)};
  reinterpret_cast<uint4*>(out)[i] = *reinterpret_cast<uint4*>(r);
}

// ================= batched alpha GEMV, both node types in one dispatch =================
struct AlphaJobs { int wslot[8]; int outOff[8]; };

template<int K>
__global__ __launch_bounds__(256) void alpha_dual(
    const ushort_t* __restrict__ XD, const ushort_t* __restrict__ XI,
    const float* __restrict__ wv, float* __restrict__ outBase,
    AlphaJobs jd, AlphaJobs ji, int gbD)
{
  const bool isD = blockIdx.x < (unsigned)gbD;
  const ushort_t* X = isD ? XD : XI;
  const int N = isD ? NDRUG : NDIS;
  const AlphaJobs jobs = isD ? jd : ji;
  int i = (isD ? blockIdx.x : blockIdx.x - gbD) * 256 + threadIdx.x;
  if (i >= N) return;
  float acc[8];
  #pragma unroll
  for (int v = 0; v < 8; ++v) acc[v] = 0.f;
  const ushort_t* xp = X + (size_t)i * K;
  for (int k = 0; k < K; k += 8) {
    uint4 u = *reinterpret_cast<const uint4*>(xp + k);
    unsigned uu[4] = {u.x, u.y, u.z, u.w};
    float xf[8];
    #pragma unroll
    for (int q = 0; q < 4; ++q) {
      xf[2 * q]     = __uint_as_float(uu[q] << 16);
      xf[2 * q + 1] = __uint_as_float(uu[q] & 0xFFFF0000u);
    }
    #pragma unroll
    for (int v = 0; v < 8; ++v) {
      const float* wp = wv + jobs.wslot[v] * 256 + k;
      #pragma unroll
      for (int q = 0; q < 8; ++q) acc[v] += xf[q] * wp[q];
    }
  }
  #pragma unroll
  for (int v = 0; v < 8; ++v) outBase[jobs.outOff[v] + i] = acc[v];
}

// ================= CSR build =================
struct RelIdx { const int* src[NREL]; const int* dst[NREL]; };
struct NdArr  { int nd[NREL]; };

__global__ void zero_ints(int* __restrict__ p, int n) {
  int i = blockIdx.x * 256 + threadIdx.x;
  if (i < n) p[i] = 0;
}
__global__ void hist_k(RelIdx ri, int* __restrict__ counts) {
  int e = blockIdx.x * 256 + threadIdx.x;
  int r = blockIdx.y;
  if (e >= NE) return;
  atomicAdd(&counts[r * RPSTR + ri.dst[r][e]], 1);
}
__global__ __launch_bounds__(256) void scan_blk(const int* __restrict__ in,
                                                int* __restrict__ partial,
                                                int* __restrict__ bsum, int n)
{
  __shared__ int ts[256];
  int t = threadIdx.x;
  int base = blockIdx.x * 1024 + t * 4;
  int v[4];
  #pragma unroll
  for (int i = 0; i < 4; ++i) v[i] = (base + i < n) ? in[base + i] : 0;
  int s = v[0] + v[1] + v[2] + v[3];
  ts[t] = s; __syncthreads();
  for (int off = 1; off < 256; off <<= 1) {
    int x = (t >= off) ? ts[t - off] : 0;
    __syncthreads();
    ts[t] += x;
    __syncthreads();
  }
  int run = ts[t] - s;
  #pragma unroll
  for (int i = 0; i < 4; ++i) {
    if (base + i < n) partial[base + i] = run;
    run += v[i];
  }
  if (t == 255) bsum[blockIdx.x] = ts[255];
}
// block bx: rowptr/cursor[bx*1024 + i] = partial[...] + sum(bsum[0..bx))
__global__ __launch_bounds__(512) void scan_fin(const int* __restrict__ partial,
                                                const int* __restrict__ bsum,
                                                int* __restrict__ rowptr,
                                                int* __restrict__ cursor, int n)
{
  __shared__ int ts[512];
  int t = threadIdx.x;
  ts[t] = (t < (int)blockIdx.x) ? bsum[t] : 0;   // nb <= 512
  __syncthreads();
  #pragma unroll
  for (int off = 256; off; off >>= 1) {
    if (t < off) ts[t] += ts[t + off];
    __syncthreads();
  }
  int base = ts[0];
  #pragma unroll
  for (int i = 0; i < 2; ++i) {
    int idx = blockIdx.x * 1024 + t + i * 512;
    if (idx < n) {
      int v = partial[idx] + base;
      rowptr[idx] = v; cursor[idx] = v;
    }
  }
}
__global__ void fill_k(RelIdx ri, int* __restrict__ cursor, int* __restrict__ colsrc) {
  int e = blockIdx.x * 256 + threadIdx.x;
  int r = blockIdx.y;
  if (e >= NE) return;
  int d = ri.dst[r][e];
  int pos = atomicAdd(&cursor[r * RPSTR + d], 1);
  colsrc[pos] = ri.src[r][e];
}

// ==== per-(rel,dst) softmax: coef[i] = NORMALIZED softmax coefficient ====
__global__ __launch_bounds__(256) void coef_k(
    const int* __restrict__ rowptr, const int* __restrict__ colsrc,
    float* __restrict__ coef, const float* __restrict__ alphaB, NdArr nds)
{
  int d = blockIdx.x * 256 + threadIdx.x;
  int r = blockIdx.y;
  if (d >= nds.nd[r]) return;
  int beg = rowptr[r * RPSTR + d], end = rowptr[r * RPSTR + d + 1];
  if (beg == end) return;
  const float ad = alphaB[(NREL + r) * NDIS + d];
  const float* as = alphaB + (size_t)r * NDIS;
  int deg = end - beg;
  if (deg <= 16) {
    float av[16];
    float m = -1e30f;
    #pragma unroll
    for (int i = 0; i < 16; ++i) {
      float a = -1e30f;
      if (i < deg) {
        int s = colsrc[beg + i];
        a = as[s] + ad;
        a = a > 0.f ? a : 0.2f * a;
      }
      av[i] = a;
      m = fmaxf(m, a);
    }
    float sum = 0.f;
    #pragma unroll
    for (int i = 0; i < 16; ++i) {
      if (i < deg) {
        float ex = __expf(av[i] - m);
        av[i] = ex;
        sum += ex;
      }
    }
    float inv = 1.f / (sum + 1e-16f);
    #pragma unroll
    for (int i = 0; i < 16; ++i)
      if (i < deg) coef[beg + i] = av[i] * inv;
  } else {
    float m = -1e30f;
    for (int i = beg; i < end; ++i) {
      float a = as[colsrc[i]] + ad;
      a = a > 0.f ? a : 0.2f * a;
      m = fmaxf(m, a);
    }
    float sum = 0.f;
    for (int i = beg; i < end; ++i) {
      float a = as[colsrc[i]] + ad;
      a = a > 0.f ? a : 0.2f * a;
      float ex = __expf(a - m);
      coef[i] = ex;
      sum += ex;
    }
    float inv = 1.f / (sum + 1e-16f);
    for (int i = beg; i < end; ++i) coef[i] *= inv;
  }
}

// ==== PV gather (exact r4 measured-best): full wave/dst, 2 cols/lane, 4-edge unroll ====
struct PvRel { int rel; int rowptr_off; const ushort_t* hs; int hst; int hoff; };
struct PvParams { PvRel dr[3]; PvRel di[4]; };

template<bool RELU>
__global__ __launch_bounds__(256) void pv_multi(
    PvParams P, const int* __restrict__ rowptr, const int* __restrict__ colsrc,
    const float* __restrict__ coef, const float* __restrict__ bias,
    ushort_t* __restrict__ outD, ushort_t* __restrict__ outI, int nbD)
{
  const int wave = threadIdx.x >> 6, lane = threadIdx.x & 63;
  const int c0 = 2 * lane;
  const bool isD = blockIdx.x < (unsigned)nbD;
  const int d = (isD ? blockIdx.x : blockIdx.x - nbD) * 4 + wave;
  const int Nd = isD ? NDRUG : NDIS;
  if (d >= Nd) return;
  const int nr = isD ? 3 : 4;
  float acc0 = 0.f, acc1 = 0.f;

  #pragma unroll
  for (int q = 0; q < 4; ++q) {
    if (q >= nr) break;
    const PvRel R = isD ? P.dr[q] : P.di[q];
    acc0 += bias[R.rel * HID + c0];
    acc1 += bias[R.rel * HID + c0 + 1];
    const int beg = rowptr[R.rowptr_off + d];
    const int end = rowptr[R.rowptr_off + d + 1];
    if (beg == end) continue;
    const ushort_t* hsb = R.hs + R.hoff + c0;
    const int hst = R.hst;
    for (int c = beg; c < end; c += 4) {
      float cf[4]; int si[4];
      #pragma unroll
      for (int j = 0; j < 4; ++j) {
        int idx = (c + j < end) ? c + j : end - 1;
        cf[j] = (c + j < end) ? coef[idx] : 0.f;
        si[j] = colsrc[idx];
      }
      ushort2 hv[4];
      #pragma unroll
      for (int j = 0; j < 4; ++j)
        hv[j] = *reinterpret_cast<const ushort2*>(hsb + (size_t)si[j] * hst);
      #pragma unroll
      for (int j = 0; j < 4; ++j) {
        acc0 += cf[j] * bf2f(hv[j].x);
        acc1 += cf[j] * bf2f(hv[j].y);
      }
    }
  }
  if (RELU) { acc0 = fmaxf(acc0, 0.f); acc1 = fmaxf(acc1, 0.f); }
  ushort2 o; o.x = f2bf(acc0); o.y = f2bf(acc1);
  ushort_t* out = isD ? outD : outI;
  *reinterpret_cast<ushort2*>(out + (size_t)d * HID + c0) = o;
}

// ================= host =================
static const int DSTh[NREL] = {1, 0, 1, 0, 1, 1, 0};

struct WsPlan {
  ushort_t *xdb1, *xib1, *xd1b, *xi1b, *xd2b, *xi2b;
  ushort_t *hs_d, *hs_i, *wcatT_d, *wcatT_i, *wfinT_d, *wfinT_i;
  float *alphaB, *wv, *coef;
  int *counts, *rowptr, *cursor, *colsrc, *bsum;
  size_t total_bytes;
};

static WsPlan plan_ws(void* d_ws) {
  WsPlan p;
  ushort_t* s = (ushort_t*)d_ws;
  p.xdb1 = s;     s += (size_t)NDRUG * 256;
  p.xib1 = s;     s += (size_t)NDIS * 256;
  p.xd1b = s;     s += (size_t)NDRUG * HID;
  p.xi1b = s;     s += (size_t)NDIS * HID;
  p.hs_d = s;     s += (size_t)NDRUG * 384;
  p.hs_i = s;     s += (size_t)NDIS * 512;
  p.wcatT_d = s;  s += 384 * 256;
  p.wcatT_i = s;  s += 512 * 256;
  p.wfinT_d = s;  s += 128 * 128;
  p.wfinT_i = s;  s += 128 * 128;
  p.xd2b = p.xdb1;   // alias: xdb1 dead after L1 GEMM/alpha
  p.xi2b = p.xib1;
  float* f = (float*)s;
  p.alphaB = f;   f += (size_t)15 * NDIS;   // 14 rows + 1 dummy
  p.wv = f;       f += 14 * 256;
  p.coef = f;     f += (size_t)NREL * NE;
  int* q = (int*)f;
  p.counts = q;   q += NS_TOT;
  p.rowptr = q;   q += NS_TOT;
  p.cursor = q;   q += NS_TOT;
  p.colsrc = q;   q += NREL * NE;
  p.bsum = q;     q += 512;
  p.total_bytes = (size_t)((char*)q - (char*)d_ws);
  return p;
}

static void run_layer(const ushort_t* XDb, const ushort_t* XIb, int K,
                      const float* Wsrc, const float* Wdst,
                      const float* as_, const float* ad_, const float* bias,
                      ushort_t* outDb, ushort_t* outIb, bool relu,
                      const WsPlan& p, hipStream_t stream)
{
  int4 rd = make_int4(0, 2, 6, 0);
  int4 ri4 = make_int4(1, 3, 4, 5);
  build_wcat2<<<(K * 896 + 255) / 256, 256, 0, stream>>>(
      Wsrc, p.wcatT_d, 384, rd, Wsrc, p.wcatT_i, 512, ri4, K);
  wvec_kernel<<<dim3(14, K / 4), 256, 0, stream>>>(Wsrc, as_, Wdst, ad_, p.wv, K);

  AlphaJobs jd = {};
  jd.wslot[0] = 0;     jd.outOff[0] = 0 * NDIS;
  jd.wslot[1] = 2;     jd.outOff[1] = 2 * NDIS;
  jd.wslot[2] = 6;     jd.outOff[2] = 6 * NDIS;
  jd.wslot[3] = 7 + 1; jd.outOff[3] = (7 + 1) * NDIS;
  jd.wslot[4] = 7 + 3; jd.outOff[4] = (7 + 3) * NDIS;
  jd.wslot[5] = 7 + 6; jd.outOff[5] = (7 + 6) * NDIS;
  jd.wslot[6] = 0;     jd.outOff[6] = 14 * NDIS;   // dummy
  jd.wslot[7] = 0;     jd.outOff[7] = 14 * NDIS;   // dummy
  AlphaJobs ji = {};
  ji.wslot[0] = 1;     ji.outOff[0] = 1 * NDIS;
  ji.wslot[1] = 3;     ji.outOff[1] = 3 * NDIS;
  ji.wslot[2] = 4;     ji.outOff[2] = 4 * NDIS;
  ji.wslot[3] = 5;     ji.outOff[3] = 5 * NDIS;
  ji.wslot[4] = 7 + 0; ji.outOff[4] = (7 + 0) * NDIS;
  ji.wslot[5] = 7 + 2; ji.outOff[5] = (7 + 2) * NDIS;
  ji.wslot[6] = 7 + 4; ji.outOff[6] = (7 + 4) * NDIS;
  ji.wslot[7] = 7 + 5; ji.outOff[7] = (7 + 5) * NDIS;
  int gbD = (NDRUG + 255) / 256, gbI = (NDIS + 255) / 256;
  if (K == 256)
    alpha_dual<256><<<gbD + gbI, 256, 0, stream>>>(XDb, XIb, p.wv, p.alphaB, jd, ji, gbD);
  else
    alpha_dual<128><<<gbD + gbI, 256, 0, stream>>>(XDb, XIb, p.wv, p.alphaB, jd, ji, gbD);

  // hs GEMMs (both node types, one dispatch; 128x128 tiles)
  GemmJob g0 = {XDb, p.wcatT_d, nullptr, p.hs_d, NDRUG, 384};
  GemmJob g1 = {XIb, p.wcatT_i, nullptr, p.hs_i, NDIS, 512};
  int gx0 = (NDRUG + 127) / 128, gx1 = (NDIS + 127) / 128;
  gemm_dual<false, false, true><<<dim3(gx0 + gx1, 4), 256, 0, stream>>>(g0, g1, gx0, K);

  // softmax coefs (normalized)
  NdArr nds;
  for (int r = 0; r < NREL; ++r) nds.nd[r] = DSTh[r] == 0 ? NDRUG : NDIS;
  coef_k<<<dim3((NDIS + 255) / 256, NREL), 256, 0, stream>>>(
      p.rowptr, p.colsrc, p.coef, p.alphaB, nds);

  // PV gather
  PvParams P;
  P.dr[0] = {1, 1 * RPSTR, p.hs_i, 512, 0};
  P.dr[1] = {3, 3 * RPSTR, p.hs_i, 512, 128};
  P.dr[2] = {6, 6 * RPSTR, p.hs_d, 384, 256};
  P.di[0] = {0, 0 * RPSTR, p.hs_d, 384, 0};
  P.di[1] = {2, 2 * RPSTR, p.hs_d, 384, 128};
  P.di[2] = {4, 4 * RPSTR, p.hs_i, 512, 256};
  P.di[3] = {5, 5 * RPSTR, p.hs_i, 512, 384};
  int nbD = (NDRUG + 3) / 4, nbI = (NDIS + 3) / 4;
  if (relu)
    pv_multi<true><<<nbD + nbI, 256, 0, stream>>>(
        P, p.rowptr, p.colsrc, p.coef, bias, outDb, outIb, nbD);
  else
    pv_multi<false><<<nbD + nbI, 256, 0, stream>>>(
        P, p.rowptr, p.colsrc, p.coef, bias, outDb, outIb, nbD);
}

extern "C" void kernel_launch(void* const* d_in, const int* in_sizes, int n_in,
                              void* d_out, int out_size, void* d_ws, size_t ws_size,
                              hipStream_t stream) {
  const float* x_drug = (const float*)d_in[0];
  const float* x_dis  = (const float*)d_in[1];
  RelIdx ri;
  for (int r = 0; r < NREL; ++r) {
    const int* e = (const int*)d_in[2 + r];
    ri.src[r] = e; ri.dst[r] = e + NE;
  }
  const float* W1s = (const float*)d_in[9];
  const float* W1d = (const float*)d_in[10];
  const float* a1s = (const float*)d_in[11];
  const float* a1d = (const float*)d_in[12];
  const float* b1  = (const float*)d_in[13];
  const float* W2s = (const float*)d_in[14];
  const float* W2d = (const float*)d_in[15];
  const float* a2s = (const float*)d_in[16];
  const float* a2d = (const float*)d_in[17];
  const float* b2  = (const float*)d_in[18];
  const float* Wdr = (const float*)d_in[19];
  const float* bdr = (const float*)d_in[20];
  const float* Wdi = (const float*)d_in[21];
  const float* bdi = (const float*)d_in[22];

  WsPlan p = plan_ws(d_ws);
  if (p.total_bytes > ws_size) return;

  cvt2_f32_bf16<<<((NDRUG + NDIS) * 256 / 8 + 255) / 256, 256, 0, stream>>>(
      x_drug, p.xdb1, NDRUG * 256 / 8, x_dis, p.xib1, NDIS * 256 / 8);

  // CSR build (reused by both layers)
  zero_ints<<<(NS_TOT + 255) / 256, 256, 0, stream>>>(p.counts, NS_TOT);
  dim3 ge((NE + 255) / 256, NREL);
  hist_k<<<ge, 256, 0, stream>>>(ri, p.counts);
  int nb = (NS_TOT + 1023) / 1024;
  scan_blk<<<nb, 256, 0, stream>>>(p.counts, p.cursor, p.bsum, NS_TOT);
  scan_fin<<<nb, 512, 0, stream>>>(p.cursor, p.bsum, p.rowptr, p.cursor, NS_TOT);
  fill_k<<<ge, 256, 0, stream>>>(ri, p.cursor, p.colsrc);

  // Layer 1 (K=256, relu), Layer 2 (K=128)
  run_layer(p.xdb1, p.xib1, 256, W1s, W1d, a1s, a1d, b1, p.xd1b, p.xi1b, true, p, stream);
  run_layer(p.xd1b, p.xi1b, 128, W2s, W2d, a2s, a2d, b2, p.xd2b, p.xi2b, false, p, stream);

  // final linear + bias + relu -> d_out (f32)
  int4 r0 = make_int4(0, 0, 0, 0);
  build_wcat2<<<(128 * 128 * 2 + 255) / 256, 256, 0, stream>>>(
      Wdr, p.wfinT_d, 128, r0, Wdi, p.wfinT_i, 128, r0, 128);
  float* out = (float*)d_out;
  GemmJob f0 = {p.xd2b, p.wfinT_d, bdr, out, NDRUG, 128};
  GemmJob f1 = {p.xi2b, p.wfinT_i, bdi, out + (size_t)NDRUG * HID, NDIS, 128};
  int gx0 = (NDRUG + 127) / 128, gx1 = (NDIS + 127) / 128;
  gemm_dual<true, true, false><<<dim3(gx0 + gx1, 1), 256, 0, stream>>>(f0, f1, gx0, 128);
}

// Round 11
// 451.900 us; speedup vs baseline: 1.2416x; 1.0415x over previous
//
#include <hip/hip_runtime.h>
#include <stdint.h>

#define NDRUG 20000
#define NDIS  40000
#define HID   128
#define NE    150000
#define NREL  7
#define RPSTR (NDIS + 1)
#define NS_TOT (NREL * RPSTR)
#define CPX   ((NE + 255) / 256)   // edge-chunks per relation

typedef unsigned short ushort_t;
typedef __attribute__((ext_vector_type(8))) short bf16x8;
typedef __attribute__((ext_vector_type(4))) float f32x4;
typedef const __attribute__((address_space(1))) void gv_t;
typedef __attribute__((address_space(3))) void lv_t;

__device__ __forceinline__ ushort_t f2bf(float f) {
  unsigned u = __float_as_uint(f);
  u += 0x7FFFu + ((u >> 16) & 1u);          // RNE
  return (ushort_t)(u >> 16);
}
__device__ __forceinline__ float bf2f(ushort_t h) {
  return __uint_as_float(((unsigned)h) << 16);
}

// ============ dual-job bf16 MFMA GEMM: C = A[M,K] @ BT[N,K]^T ============
// 128x128 tile, 4 waves, 2-phase prefetch (double-buffered LDS, 1 barrier/step).
struct GemmJob { const ushort_t* A; const ushort_t* BT; const float* bias; void* C; int M, N; };

template<bool BIAS, bool RELU, bool BF16OUT>
__global__ __launch_bounds__(256) void gemm_dual(GemmJob j0, GemmJob j1, int gx0, int K)
{
  __shared__ ushort_t As[2][128 * 32];
  __shared__ ushort_t Bs[2][128 * 32];
  const bool first = blockIdx.x < (unsigned)gx0;
  const GemmJob J = first ? j0 : j1;
  const int bx = first ? blockIdx.x : blockIdx.x - gx0;
  if ((int)blockIdx.y * 128 >= J.N) return;   // uniform exit, before any sync
  const int tid = threadIdx.x;
  const int m0 = bx * 128;
  const int n0 = blockIdx.y * 128;
  const int wave = tid >> 6, lane = tid & 63;
  const int wm = wave & 1, wn = wave >> 1;
  const int l15 = lane & 15, lk = lane >> 4;

  const int rowS = wave * 16 + (lane >> 2);
  const int chunk = (lane & 3) * 8;
  const ushort_t* ga0 = J.A + (size_t)min(m0 + rowS, J.M - 1) * K + chunk;
  const ushort_t* ga1 = J.A + (size_t)min(m0 + rowS + 64, J.M - 1) * K + chunk;
  const ushort_t* gb0 = J.BT + (size_t)(n0 + rowS) * K + chunk;
  const ushort_t* gb1 = J.BT + (size_t)(n0 + rowS + 64) * K + chunk;

#define GEMM_STAGE(buf, koff)                                                              \
  do {                                                                                     \
    __builtin_amdgcn_global_load_lds((gv_t*)(ga0 + (koff)), (lv_t*)(&As[buf][wave * 512]), 16, 0, 0);        \
    __builtin_amdgcn_global_load_lds((gv_t*)(ga1 + (koff)), (lv_t*)(&As[buf][wave * 512 + 2048]), 16, 0, 0); \
    __builtin_amdgcn_global_load_lds((gv_t*)(gb0 + (koff)), (lv_t*)(&Bs[buf][wave * 512]), 16, 0, 0);        \
    __builtin_amdgcn_global_load_lds((gv_t*)(gb1 + (koff)), (lv_t*)(&Bs[buf][wave * 512 + 2048]), 16, 0, 0); \
  } while (0)

  f32x4 acc[4][4] = {};
  const int nt = K >> 5;

  GEMM_STAGE(0, 0);
  __syncthreads();                       // tile 0 landed

  for (int t = 0; t < nt; ++t) {
    if (t + 1 < nt) GEMM_STAGE((t + 1) & 1, (t + 1) * 32);
    const ushort_t* Ab = As[t & 1];
    const ushort_t* Bb = Bs[t & 1];
    bf16x8 af[4], bfg[4];
    #pragma unroll
    for (int m = 0; m < 4; ++m)
      af[m] = *reinterpret_cast<const bf16x8*>(&Ab[(wm * 64 + m * 16 + l15) * 32 + lk * 8]);
    #pragma unroll
    for (int n = 0; n < 4; ++n)
      bfg[n] = *reinterpret_cast<const bf16x8*>(&Bb[(wn * 64 + n * 16 + l15) * 32 + lk * 8]);
    #pragma unroll
    for (int m = 0; m < 4; ++m)
      #pragma unroll
      for (int n = 0; n < 4; ++n)
        acc[m][n] = __builtin_amdgcn_mfma_f32_16x16x32_bf16(af[m], bfg[n], acc[m][n], 0, 0, 0);
    __syncthreads();
  }
#undef GEMM_STAGE

  #pragma unroll
  for (int m = 0; m < 4; ++m) {
    int rbase = m0 + wm * 64 + m * 16 + lk * 4;
    #pragma unroll
    for (int n = 0; n < 4; ++n) {
      int col = n0 + wn * 64 + n * 16 + l15;
      float bv = 0.f;
      if (BIAS) bv = J.bias[col];
      #pragma unroll
      for (int j = 0; j < 4; ++j) {
        int row = rbase + j;
        if (row >= J.M) continue;
        float v = acc[m][n][j] + bv;
        if (RELU) v = fmaxf(v, 0.f);
        if (BF16OUT) ((ushort_t*)J.C)[(size_t)row * J.N + col] = f2bf(v);
        else         ((float*)J.C)[(size_t)row * J.N + col] = v;
      }
    }
  }
}

// ================= weight prep (two outputs in one dispatch) =================
__global__ void build_wcat2(const float* __restrict__ WA, ushort_t* __restrict__ outA,
                            int ncolA, int4 relsA,
                            const float* __restrict__ WB, ushort_t* __restrict__ outB,
                            int ncolB, int4 relsB, int K)
{
  int id = blockIdx.x * 256 + threadIdx.x;
  const float* W; ushort_t* out; int ncol; int4 rels;
  int totA = K * ncolA;
  if (id < totA) { W = WA; out = outA; ncol = ncolA; rels = relsA; }
  else {
    id -= totA;
    if (id >= K * ncolB) return;
    W = WB; out = outB; ncol = ncolB; rels = relsB;
  }
  int k = id / ncol, c = id - k * ncol;
  int rr = (&rels.x)[c >> 7];
  out[(size_t)c * K + k] = f2bf(W[((size_t)rr * K + k) * HID + (c & 127)]);
}

// wv[slot][k] = sum_j W[r][k][j] * a[r][j]   (slot<7: src, else dst)
__global__ __launch_bounds__(256) void wvec_kernel(
    const float* __restrict__ Wsrc, const float* __restrict__ as_,
    const float* __restrict__ Wdst, const float* __restrict__ ad_,
    float* __restrict__ wv, int K)
{
  int slot = blockIdx.x;
  int r = slot % NREL;
  const float* W = (slot < NREL ? Wsrc : Wdst) + (size_t)r * K * HID;
  const float* a = (slot < NREL ? as_ : ad_) + r * HID;
  int wave = threadIdx.x >> 6, lane = threadIdx.x & 63;
  int k = blockIdx.y * 4 + wave;
  if (k >= K) return;
  float s = W[(size_t)k * HID + lane] * a[lane]
          + W[(size_t)k * HID + 64 + lane] * a[64 + lane];
  #pragma unroll
  for (int off = 32; off; off >>= 1) s += __shfl_xor(s, off);
  if (lane == 0) wv[slot * 256 + k] = s;
}

// ================= f32 -> bf16 convert (two tensors, one dispatch) =================
__global__ void cvt2_f32_bf16(const float* __restrict__ inA, ushort_t* __restrict__ outA, int n8A,
                              const float* __restrict__ inB, ushort_t* __restrict__ outB, int n8B)
{
  int i = blockIdx.x * 256 + threadIdx.x;
  const float* in; ushort_t* out;
  if (i < n8A) { in = inA; out = outA; }
  else {
    i -= n8A;
    if (i >= n8B) return;
    in = inB; out = outB;
  }
  float4 a = reinterpret_cast<const float4*>(in)[2 * i];
  float4 b = reinterpret_cast<const float4*>(in)[2 * i + 1];
  ushort_t r[8] = {f2bf(a.x), f2bf(a.y), f2bf(a.z), f2bf(a.w),
                   f2bf(b.x), f2bf(b.y), f2bf(b.z), f2bf(b.w)};
  reinterpret_cast<uint4*>(out)[i] = *reinterpret_cast<uint4*>(r);
}

// ================= batched alpha GEMV, both node types in one dispatch =================
struct AlphaJobs { int wslot[8]; int outOff[8]; };

template<int K>
__global__ __launch_bounds__(256) void alpha_dual(
    const ushort_t* __restrict__ XD, const ushort_t* __restrict__ XI,
    const float* __restrict__ wv, float* __restrict__ outBase,
    AlphaJobs jd, AlphaJobs ji, int gbD)
{
  const bool isD = blockIdx.x < (unsigned)gbD;
  const ushort_t* X = isD ? XD : XI;
  const int N = isD ? NDRUG : NDIS;
  const AlphaJobs jobs = isD ? jd : ji;
  int i = (isD ? blockIdx.x : blockIdx.x - gbD) * 256 + threadIdx.x;
  if (i >= N) return;
  float acc[8];
  #pragma unroll
  for (int v = 0; v < 8; ++v) acc[v] = 0.f;
  const ushort_t* xp = X + (size_t)i * K;
  for (int k = 0; k < K; k += 8) {
    uint4 u = *reinterpret_cast<const uint4*>(xp + k);
    unsigned uu[4] = {u.x, u.y, u.z, u.w};
    float xf[8];
    #pragma unroll
    for (int q = 0; q < 4; ++q) {
      xf[2 * q]     = __uint_as_float(uu[q] << 16);
      xf[2 * q + 1] = __uint_as_float(uu[q] & 0xFFFF0000u);
    }
    #pragma unroll
    for (int v = 0; v < 8; ++v) {
      const float* wp = wv + jobs.wslot[v] * 256 + k;
      #pragma unroll
      for (int q = 0; q < 8; ++q) acc[v] += xf[q] * wp[q];
    }
  }
  #pragma unroll
  for (int v = 0; v < 8; ++v) outBase[jobs.outOff[v] + i] = acc[v];
}

// ================= CSR build =================
struct RelIdx { const int* src[NREL]; const int* dst[NREL]; };
struct NdArr  { int nd[NREL]; };

__global__ void zero_ints(int* __restrict__ p, int n) {
  int i = blockIdx.x * 256 + threadIdx.x;
  if (i < n) p[i] = 0;
}
// XCD-pinned: blockIdx.x & 7 selects XCD (round-robin dispatch heuristic);
// relation r handled only by blocks on XCD r -> counts/colsrc region for r
// is written from ONE XCD's L2, killing partial-line writeback amplification.
__global__ void hist_k(RelIdx ri, int* __restrict__ counts) {
  int xcd = blockIdx.x & 7;
  if (xcd >= NREL) return;
  int e = (blockIdx.x >> 3) * 256 + threadIdx.x;
  if (e >= NE) return;
  atomicAdd(&counts[xcd * RPSTR + ri.dst[xcd][e]], 1);
}
__global__ __launch_bounds__(256) void scan_blk(const int* __restrict__ in,
                                                int* __restrict__ partial,
                                                int* __restrict__ bsum, int n)
{
  __shared__ int ts[256];
  int t = threadIdx.x;
  int base = blockIdx.x * 1024 + t * 4;
  int v[4];
  #pragma unroll
  for (int i = 0; i < 4; ++i) v[i] = (base + i < n) ? in[base + i] : 0;
  int s = v[0] + v[1] + v[2] + v[3];
  ts[t] = s; __syncthreads();
  for (int off = 1; off < 256; off <<= 1) {
    int x = (t >= off) ? ts[t - off] : 0;
    __syncthreads();
    ts[t] += x;
    __syncthreads();
  }
  int run = ts[t] - s;
  #pragma unroll
  for (int i = 0; i < 4; ++i) {
    if (base + i < n) partial[base + i] = run;
    run += v[i];
  }
  if (t == 255) bsum[blockIdx.x] = ts[255];
}
__global__ __launch_bounds__(512) void scan_fin(const int* __restrict__ partial,
                                                const int* __restrict__ bsum,
                                                int* __restrict__ rowptr,
                                                int* __restrict__ cursor, int n)
{
  __shared__ int ts[512];
  int t = threadIdx.x;
  ts[t] = (t < (int)blockIdx.x) ? bsum[t] : 0;   // nb <= 512
  __syncthreads();
  #pragma unroll
  for (int off = 256; off; off >>= 1) {
    if (t < off) ts[t] += ts[t + off];
    __syncthreads();
  }
  int base = ts[0];
  #pragma unroll
  for (int i = 0; i < 2; ++i) {
    int idx = blockIdx.x * 1024 + t + i * 512;
    if (idx < n) {
      int v = partial[idx] + base;
      rowptr[idx] = v; cursor[idx] = v;
    }
  }
}
// XCD-pinned scatter (see hist_k comment): colsrc writes for relation r come
// from one XCD -> its L2 accumulates ~16 stores/line before a single writeback.
__global__ void fill_k(RelIdx ri, int* __restrict__ cursor, int* __restrict__ colsrc) {
  int xcd = blockIdx.x & 7;
  if (xcd >= NREL) return;
  int e = (blockIdx.x >> 3) * 256 + threadIdx.x;
  if (e >= NE) return;
  int d = ri.dst[xcd][e];
  int pos = atomicAdd(&cursor[xcd * RPSTR + d], 1);
  colsrc[pos] = ri.src[xcd][e];
}

// ==== per-(rel,dst) softmax: coef[i] = NORMALIZED softmax coefficient ====
__global__ __launch_bounds__(256) void coef_k(
    const int* __restrict__ rowptr, const int* __restrict__ colsrc,
    float* __restrict__ coef, const float* __restrict__ alphaB, NdArr nds)
{
  int d = blockIdx.x * 256 + threadIdx.x;
  int r = blockIdx.y;
  if (d >= nds.nd[r]) return;
  int beg = rowptr[r * RPSTR + d], end = rowptr[r * RPSTR + d + 1];
  if (beg == end) return;
  const float ad = alphaB[(NREL + r) * NDIS + d];
  const float* as = alphaB + (size_t)r * NDIS;
  int deg = end - beg;
  if (deg <= 16) {
    float av[16];
    float m = -1e30f;
    #pragma unroll
    for (int i = 0; i < 16; ++i) {
      float a = -1e30f;
      if (i < deg) {
        int s = colsrc[beg + i];
        a = as[s] + ad;
        a = a > 0.f ? a : 0.2f * a;
      }
      av[i] = a;
      m = fmaxf(m, a);
    }
    float sum = 0.f;
    #pragma unroll
    for (int i = 0; i < 16; ++i) {
      if (i < deg) {
        float ex = __expf(av[i] - m);
        av[i] = ex;
        sum += ex;
      }
    }
    float inv = 1.f / (sum + 1e-16f);
    #pragma unroll
    for (int i = 0; i < 16; ++i)
      if (i < deg) coef[beg + i] = av[i] * inv;
  } else {
    float m = -1e30f;
    for (int i = beg; i < end; ++i) {
      float a = as[colsrc[i]] + ad;
      a = a > 0.f ? a : 0.2f * a;
      m = fmaxf(m, a);
    }
    float sum = 0.f;
    for (int i = beg; i < end; ++i) {
      float a = as[colsrc[i]] + ad;
      a = a > 0.f ? a : 0.2f * a;
      float ex = __expf(a - m);
      coef[i] = ex;
      sum += ex;
    }
    float inv = 1.f / (sum + 1e-16f);
    for (int i = beg; i < end; ++i) coef[i] *= inv;
  }
}

// ==== PV gather (measured-best r4/r10): full wave/dst, 2 cols/lane, 4-edge unroll ====
struct PvRel { int rel; int rowptr_off; const ushort_t* hs; int hst; int hoff; };
struct PvParams { PvRel dr[3]; PvRel di[4]; };

template<bool RELU>
__global__ __launch_bounds__(256) void pv_multi(
    PvParams P, const int* __restrict__ rowptr, const int* __restrict__ colsrc,
    const float* __restrict__ coef, const float* __restrict__ bias,
    ushort_t* __restrict__ outD, ushort_t* __restrict__ outI, int nbD)
{
  const int wave = threadIdx.x >> 6, lane = threadIdx.x & 63;
  const int c0 = 2 * lane;
  const bool isD = blockIdx.x < (unsigned)nbD;
  const int d = (isD ? blockIdx.x : blockIdx.x - nbD) * 4 + wave;
  const int Nd = isD ? NDRUG : NDIS;
  if (d >= Nd) return;
  const int nr = isD ? 3 : 4;
  float acc0 = 0.f, acc1 = 0.f;

  #pragma unroll
  for (int q = 0; q < 4; ++q) {
    if (q >= nr) break;
    const PvRel R = isD ? P.dr[q] : P.di[q];
    acc0 += bias[R.rel * HID + c0];
    acc1 += bias[R.rel * HID + c0 + 1];
    const int beg = rowptr[R.rowptr_off + d];
    const int end = rowptr[R.rowptr_off + d + 1];
    if (beg == end) continue;
    const ushort_t* hsb = R.hs + R.hoff + c0;
    const int hst = R.hst;
    for (int c = beg; c < end; c += 4) {
      float cf[4]; int si[4];
      #pragma unroll
      for (int j = 0; j < 4; ++j) {
        int idx = (c + j < end) ? c + j : end - 1;
        cf[j] = (c + j < end) ? coef[idx] : 0.f;
        si[j] = colsrc[idx];
      }
      ushort2 hv[4];
      #pragma unroll
      for (int j = 0; j < 4; ++j)
        hv[j] = *reinterpret_cast<const ushort2*>(hsb + (size_t)si[j] * hst);
      #pragma unroll
      for (int j = 0; j < 4; ++j) {
        acc0 += cf[j] * bf2f(hv[j].x);
        acc1 += cf[j] * bf2f(hv[j].y);
      }
    }
  }
  if (RELU) { acc0 = fmaxf(acc0, 0.f); acc1 = fmaxf(acc1, 0.f); }
  ushort2 o; o.x = f2bf(acc0); o.y = f2bf(acc1);
  ushort_t* out = isD ? outD : outI;
  *reinterpret_cast<ushort2*>(out + (size_t)d * HID + c0) = o;
}

// ================= host =================
static const int DSTh[NREL] = {1, 0, 1, 0, 1, 1, 0};

struct WsPlan {
  ushort_t *xdb1, *xib1, *xd1b, *xi1b, *xd2b, *xi2b;
  ushort_t *hs_d, *hs_i, *wcatT_d, *wcatT_i, *wfinT_d, *wfinT_i;
  float *alphaB, *wv, *coef;
  int *counts, *rowptr, *cursor, *colsrc, *bsum;
  size_t total_bytes;
};

static WsPlan plan_ws(void* d_ws) {
  WsPlan p;
  ushort_t* s = (ushort_t*)d_ws;
  p.xdb1 = s;     s += (size_t)NDRUG * 256;
  p.xib1 = s;     s += (size_t)NDIS * 256;
  p.xd1b = s;     s += (size_t)NDRUG * HID;
  p.xi1b = s;     s += (size_t)NDIS * HID;
  p.hs_d = s;     s += (size_t)NDRUG * 384;
  p.hs_i = s;     s += (size_t)NDIS * 512;
  p.wcatT_d = s;  s += 384 * 256;
  p.wcatT_i = s;  s += 512 * 256;
  p.wfinT_d = s;  s += 128 * 128;
  p.wfinT_i = s;  s += 128 * 128;
  p.xd2b = p.xdb1;   // alias: xdb1 dead after L1 GEMM/alpha
  p.xi2b = p.xib1;
  float* f = (float*)s;
  p.alphaB = f;   f += (size_t)15 * NDIS;   // 14 rows + 1 dummy
  p.wv = f;       f += 14 * 256;
  p.coef = f;     f += (size_t)NREL * NE;
  int* q = (int*)f;
  p.counts = q;   q += NS_TOT;
  p.rowptr = q;   q += NS_TOT;
  p.cursor = q;   q += NS_TOT;
  p.colsrc = q;   q += NREL * NE;
  p.bsum = q;     q += 512;
  p.total_bytes = (size_t)((char*)q - (char*)d_ws);
  return p;
}

static void run_layer(const ushort_t* XDb, const ushort_t* XIb, int K,
                      const float* Wsrc, const float* Wdst,
                      const float* as_, const float* ad_, const float* bias,
                      ushort_t* outDb, ushort_t* outIb, bool relu,
                      const WsPlan& p, hipStream_t stream)
{
  int4 rd = make_int4(0, 2, 6, 0);
  int4 ri4 = make_int4(1, 3, 4, 5);
  build_wcat2<<<(K * 896 + 255) / 256, 256, 0, stream>>>(
      Wsrc, p.wcatT_d, 384, rd, Wsrc, p.wcatT_i, 512, ri4, K);
  wvec_kernel<<<dim3(14, K / 4), 256, 0, stream>>>(Wsrc, as_, Wdst, ad_, p.wv, K);

  AlphaJobs jd = {};
  jd.wslot[0] = 0;     jd.outOff[0] = 0 * NDIS;
  jd.wslot[1] = 2;     jd.outOff[1] = 2 * NDIS;
  jd.wslot[2] = 6;     jd.outOff[2] = 6 * NDIS;
  jd.wslot[3] = 7 + 1; jd.outOff[3] = (7 + 1) * NDIS;
  jd.wslot[4] = 7 + 3; jd.outOff[4] = (7 + 3) * NDIS;
  jd.wslot[5] = 7 + 6; jd.outOff[5] = (7 + 6) * NDIS;
  jd.wslot[6] = 0;     jd.outOff[6] = 14 * NDIS;   // dummy
  jd.wslot[7] = 0;     jd.outOff[7] = 14 * NDIS;   // dummy
  AlphaJobs ji = {};
  ji.wslot[0] = 1;     ji.outOff[0] = 1 * NDIS;
  ji.wslot[1] = 3;     ji.outOff[1] = 3 * NDIS;
  ji.wslot[2] = 4;     ji.outOff[2] = 4 * NDIS;
  ji.wslot[3] = 5;     ji.outOff[3] = 5 * NDIS;
  ji.wslot[4] = 7 + 0; ji.outOff[4] = (7 + 0) * NDIS;
  ji.wslot[5] = 7 + 2; ji.outOff[5] = (7 + 2) * NDIS;
  ji.wslot[6] = 7 + 4; ji.outOff[6] = (7 + 4) * NDIS;
  ji.wslot[7] = 7 + 5; ji.outOff[7] = (7 + 5) * NDIS;
  int gbD = (NDRUG + 255) / 256, gbI = (NDIS + 255) / 256;
  if (K == 256)
    alpha_dual<256><<<gbD + gbI, 256, 0, stream>>>(XDb, XIb, p.wv, p.alphaB, jd, ji, gbD);
  else
    alpha_dual<128><<<gbD + gbI, 256, 0, stream>>>(XDb, XIb, p.wv, p.alphaB, jd, ji, gbD);

  // hs GEMMs (both node types, one dispatch; 128x128 tiles)
  GemmJob g0 = {XDb, p.wcatT_d, nullptr, p.hs_d, NDRUG, 384};
  GemmJob g1 = {XIb, p.wcatT_i, nullptr, p.hs_i, NDIS, 512};
  int gx0 = (NDRUG + 127) / 128, gx1 = (NDIS + 127) / 128;
  gemm_dual<false, false, true><<<dim3(gx0 + gx1, 4), 256, 0, stream>>>(g0, g1, gx0, K);

  // softmax coefs (normalized)
  NdArr nds;
  for (int r = 0; r < NREL; ++r) nds.nd[r] = DSTh[r] == 0 ? NDRUG : NDIS;
  coef_k<<<dim3((NDIS + 255) / 256, NREL), 256, 0, stream>>>(
      p.rowptr, p.colsrc, p.coef, p.alphaB, nds);

  // PV gather
  PvParams P;
  P.dr[0] = {1, 1 * RPSTR, p.hs_i, 512, 0};
  P.dr[1] = {3, 3 * RPSTR, p.hs_i, 512, 128};
  P.dr[2] = {6, 6 * RPSTR, p.hs_d, 384, 256};
  P.di[0] = {0, 0 * RPSTR, p.hs_d, 384, 0};
  P.di[1] = {2, 2 * RPSTR, p.hs_d, 384, 128};
  P.di[2] = {4, 4 * RPSTR, p.hs_i, 512, 256};
  P.di[3] = {5, 5 * RPSTR, p.hs_i, 512, 384};
  int nbD = (NDRUG + 3) / 4, nbI = (NDIS + 3) / 4;
  if (relu)
    pv_multi<true><<<nbD + nbI, 256, 0, stream>>>(
        P, p.rowptr, p.colsrc, p.coef, bias, outDb, outIb, nbD);
  else
    pv_multi<false><<<nbD + nbI, 256, 0, stream>>>(
        P, p.rowptr, p.colsrc, p.coef, bias, outDb, outIb, nbD);
}

extern "C" void kernel_launch(void* const* d_in, const int* in_sizes, int n_in,
                              void* d_out, int out_size, void* d_ws, size_t ws_size,
                              hipStream_t stream) {
  const float* x_drug = (const float*)d_in[0];
  const float* x_dis  = (const float*)d_in[1];
  RelIdx ri;
  for (int r = 0; r < NREL; ++r) {
    const int* e = (const int*)d_in[2 + r];
    ri.src[r] = e; ri.dst[r] = e + NE;
  }
  const float* W1s = (const float*)d_in[9];
  const float* W1d = (const float*)d_in[10];
  const float* a1s = (const float*)d_in[11];
  const float* a1d = (const float*)d_in[12];
  const float* b1  = (const float*)d_in[13];
  const float* W2s = (const float*)d_in[14];
  const float* W2d = (const float*)d_in[15];
  const float* a2s = (const float*)d_in[16];
  const float* a2d = (const float*)d_in[17];
  const float* b2  = (const float*)d_in[18];
  const float* Wdr = (const float*)d_in[19];
  const float* bdr = (const float*)d_in[20];
  const float* Wdi = (const float*)d_in[21];
  const float* bdi = (const float*)d_in[22];

  WsPlan p = plan_ws(d_ws);
  if (p.total_bytes > ws_size) return;

  cvt2_f32_bf16<<<((NDRUG + NDIS) * 256 / 8 + 255) / 256, 256, 0, stream>>>(
      x_drug, p.xdb1, NDRUG * 256 / 8, x_dis, p.xib1, NDIS * 256 / 8);

  // CSR build (reused by both layers); hist/fill XCD-pinned per relation
  zero_ints<<<(NS_TOT + 255) / 256, 256, 0, stream>>>(p.counts, NS_TOT);
  hist_k<<<8 * CPX, 256, 0, stream>>>(ri, p.counts);
  int nb = (NS_TOT + 1023) / 1024;
  scan_blk<<<nb, 256, 0, stream>>>(p.counts, p.cursor, p.bsum, NS_TOT);
  scan_fin<<<nb, 512, 0, stream>>>(p.cursor, p.bsum, p.rowptr, p.cursor, NS_TOT);
  fill_k<<<8 * CPX, 256, 0, stream>>>(ri, p.cursor, p.colsrc);

  // Layer 1 (K=256, relu), Layer 2 (K=128)
  run_layer(p.xdb1, p.xib1, 256, W1s, W1d, a1s, a1d, b1, p.xd1b, p.xi1b, true, p, stream);
  run_layer(p.xd1b, p.xi1b, 128, W2s, W2d, a2s, a2d, b2, p.xd2b, p.xi2b, false, p, stream);

  // final linear + bias + relu -> d_out (f32)
  int4 r0 = make_int4(0, 0, 0, 0);
  build_wcat2<<<(128 * 128 * 2 + 255) / 256, 256, 0, stream>>>(
      Wdr, p.wfinT_d, 128, r0, Wdi, p.wfinT_i, 128, r0, 128);
  float* out = (float*)d_out;
  GemmJob f0 = {p.xd2b, p.wfinT_d, bdr, out, NDRUG, 128};
  GemmJob f1 = {p.xi2b, p.wfinT_i, bdi, out + (size_t)NDRUG * HID, NDIS, 128};
  int gx0 = (NDRUG + 127) / 128, gx1 = (NDIS + 127) / 128;
  gemm_dual<true, true, false><<<dim3(gx0 + gx1, 1), 256, 0, stream>>>(f0, f1, gx0, 128);
}

// Round 12
// 443.180 us; speedup vs baseline: 1.2660x; 1.0197x over previous
//
#include <hip/hip_runtime.h>
#include <stdint.h>

#define NDRUG 20000
#define NDIS  40000
#define HID   128
#define NE    150000
#define NREL  7
#define RPSTR (NDIS + 1)
#define NS_TOT (NREL * RPSTR)
#define CPX   ((NE + 255) / 256)   // edge-chunks per relation

typedef unsigned short ushort_t;
typedef __attribute__((ext_vector_type(8))) short bf16x8;
typedef __attribute__((ext_vector_type(4))) float f32x4;
typedef const __attribute__((address_space(1))) void gv_t;
typedef __attribute__((address_space(3))) void lv_t;

__device__ __forceinline__ ushort_t f2bf(float f) {
  unsigned u = __float_as_uint(f);
  u += 0x7FFFu + ((u >> 16) & 1u);          // RNE
  return (ushort_t)(u >> 16);
}
__device__ __forceinline__ float bf2f(ushort_t h) {
  return __uint_as_float(((unsigned)h) << 16);
}

// ============ dual-job bf16 MFMA GEMM: C = A[M,K] @ BT[N,K]^T ============
// 128x128 tile, 4 waves, 2-phase prefetch (double-buffered LDS, 1 barrier/step).
struct GemmJob { const ushort_t* A; const ushort_t* BT; const float* bias; void* C; int M, N; };

template<bool BIAS, bool RELU, bool BF16OUT>
__global__ __launch_bounds__(256) void gemm_dual(GemmJob j0, GemmJob j1, int gx0, int K)
{
  __shared__ ushort_t As[2][128 * 32];
  __shared__ ushort_t Bs[2][128 * 32];
  const bool first = blockIdx.x < (unsigned)gx0;
  const GemmJob J = first ? j0 : j1;
  const int bx = first ? blockIdx.x : blockIdx.x - gx0;
  if ((int)blockIdx.y * 128 >= J.N) return;   // uniform exit, before any sync
  const int tid = threadIdx.x;
  const int m0 = bx * 128;
  const int n0 = blockIdx.y * 128;
  const int wave = tid >> 6, lane = tid & 63;
  const int wm = wave & 1, wn = wave >> 1;
  const int l15 = lane & 15, lk = lane >> 4;

  const int rowS = wave * 16 + (lane >> 2);
  const int chunk = (lane & 3) * 8;
  const ushort_t* ga0 = J.A + (size_t)min(m0 + rowS, J.M - 1) * K + chunk;
  const ushort_t* ga1 = J.A + (size_t)min(m0 + rowS + 64, J.M - 1) * K + chunk;
  const ushort_t* gb0 = J.BT + (size_t)(n0 + rowS) * K + chunk;
  const ushort_t* gb1 = J.BT + (size_t)(n0 + rowS + 64) * K + chunk;

#define GEMM_STAGE(buf, koff)                                                              \
  do {                                                                                     \
    __builtin_amdgcn_global_load_lds((gv_t*)(ga0 + (koff)), (lv_t*)(&As[buf][wave * 512]), 16, 0, 0);        \
    __builtin_amdgcn_global_load_lds((gv_t*)(ga1 + (koff)), (lv_t*)(&As[buf][wave * 512 + 2048]), 16, 0, 0); \
    __builtin_amdgcn_global_load_lds((gv_t*)(gb0 + (koff)), (lv_t*)(&Bs[buf][wave * 512]), 16, 0, 0);        \
    __builtin_amdgcn_global_load_lds((gv_t*)(gb1 + (koff)), (lv_t*)(&Bs[buf][wave * 512 + 2048]), 16, 0, 0); \
  } while (0)

  f32x4 acc[4][4] = {};
  const int nt = K >> 5;

  GEMM_STAGE(0, 0);
  __syncthreads();                       // tile 0 landed

  for (int t = 0; t < nt; ++t) {
    if (t + 1 < nt) GEMM_STAGE((t + 1) & 1, (t + 1) * 32);
    const ushort_t* Ab = As[t & 1];
    const ushort_t* Bb = Bs[t & 1];
    bf16x8 af[4], bfg[4];
    #pragma unroll
    for (int m = 0; m < 4; ++m)
      af[m] = *reinterpret_cast<const bf16x8*>(&Ab[(wm * 64 + m * 16 + l15) * 32 + lk * 8]);
    #pragma unroll
    for (int n = 0; n < 4; ++n)
      bfg[n] = *reinterpret_cast<const bf16x8*>(&Bb[(wn * 64 + n * 16 + l15) * 32 + lk * 8]);
    #pragma unroll
    for (int m = 0; m < 4; ++m)
      #pragma unroll
      for (int n = 0; n < 4; ++n)
        acc[m][n] = __builtin_amdgcn_mfma_f32_16x16x32_bf16(af[m], bfg[n], acc[m][n], 0, 0, 0);
    __syncthreads();
  }
#undef GEMM_STAGE

  #pragma unroll
  for (int m = 0; m < 4; ++m) {
    int rbase = m0 + wm * 64 + m * 16 + lk * 4;
    #pragma unroll
    for (int n = 0; n < 4; ++n) {
      int col = n0 + wn * 64 + n * 16 + l15;
      float bv = 0.f;
      if (BIAS) bv = J.bias[col];
      #pragma unroll
      for (int j = 0; j < 4; ++j) {
        int row = rbase + j;
        if (row >= J.M) continue;
        float v = acc[m][n][j] + bv;
        if (RELU) v = fmaxf(v, 0.f);
        if (BF16OUT) ((ushort_t*)J.C)[(size_t)row * J.N + col] = f2bf(v);
        else         ((float*)J.C)[(size_t)row * J.N + col] = v;
      }
    }
  }
}

// ================= weight prep (two outputs in one dispatch) =================
__global__ void build_wcat2(const float* __restrict__ WA, ushort_t* __restrict__ outA,
                            int ncolA, int4 relsA,
                            const float* __restrict__ WB, ushort_t* __restrict__ outB,
                            int ncolB, int4 relsB, int K)
{
  int id = blockIdx.x * 256 + threadIdx.x;
  const float* W; ushort_t* out; int ncol; int4 rels;
  int totA = K * ncolA;
  if (id < totA) { W = WA; out = outA; ncol = ncolA; rels = relsA; }
  else {
    id -= totA;
    if (id >= K * ncolB) return;
    W = WB; out = outB; ncol = ncolB; rels = relsB;
  }
  int k = id / ncol, c = id - k * ncol;
  int rr = (&rels.x)[c >> 7];
  out[(size_t)c * K + k] = f2bf(W[((size_t)rr * K + k) * HID + (c & 127)]);
}

// wv[slot][k] = sum_j W[r][k][j] * a[r][j]   (slot<7: src, else dst)
__global__ __launch_bounds__(256) void wvec_kernel(
    const float* __restrict__ Wsrc, const float* __restrict__ as_,
    const float* __restrict__ Wdst, const float* __restrict__ ad_,
    float* __restrict__ wv, int K)
{
  int slot = blockIdx.x;
  int r = slot % NREL;
  const float* W = (slot < NREL ? Wsrc : Wdst) + (size_t)r * K * HID;
  const float* a = (slot < NREL ? as_ : ad_) + r * HID;
  int wave = threadIdx.x >> 6, lane = threadIdx.x & 63;
  int k = blockIdx.y * 4 + wave;
  if (k >= K) return;
  float s = W[(size_t)k * HID + lane] * a[lane]
          + W[(size_t)k * HID + 64 + lane] * a[64 + lane];
  #pragma unroll
  for (int off = 32; off; off >>= 1) s += __shfl_xor(s, off);
  if (lane == 0) wv[slot * 256 + k] = s;
}

// ================= f32 -> bf16 convert (two tensors, one dispatch) =================
__global__ void cvt2_f32_bf16(const float* __restrict__ inA, ushort_t* __restrict__ outA, int n8A,
                              const float* __restrict__ inB, ushort_t* __restrict__ outB, int n8B)
{
  int i = blockIdx.x * 256 + threadIdx.x;
  const float* in; ushort_t* out;
  if (i < n8A) { in = inA; out = outA; }
  else {
    i -= n8A;
    if (i >= n8B) return;
    in = inB; out = outB;
  }
  float4 a = reinterpret_cast<const float4*>(in)[2 * i];
  float4 b = reinterpret_cast<const float4*>(in)[2 * i + 1];
  ushort_t r[8] = {f2bf(a.x), f2bf(a.y), f2bf(a.z), f2bf(a.w),
                   f2bf(b.x), f2bf(b.y), f2bf(b.z), f2bf(b.w)};
  reinterpret_cast<uint4*>(out)[i] = *reinterpret_cast<uint4*>(r);
}

// ================= batched alpha GEMV, both node types in one dispatch =================
struct AlphaJobs { int wslot[8]; int outOff[8]; };

template<int K>
__global__ __launch_bounds__(256) void alpha_dual(
    const ushort_t* __restrict__ XD, const ushort_t* __restrict__ XI,
    const float* __restrict__ wv, float* __restrict__ outBase,
    AlphaJobs jd, AlphaJobs ji, int gbD)
{
  const bool isD = blockIdx.x < (unsigned)gbD;
  const ushort_t* X = isD ? XD : XI;
  const int N = isD ? NDRUG : NDIS;
  const AlphaJobs jobs = isD ? jd : ji;
  int i = (isD ? blockIdx.x : blockIdx.x - gbD) * 256 + threadIdx.x;
  if (i >= N) return;
  float acc[8];
  #pragma unroll
  for (int v = 0; v < 8; ++v) acc[v] = 0.f;
  const ushort_t* xp = X + (size_t)i * K;
  for (int k = 0; k < K; k += 8) {
    uint4 u = *reinterpret_cast<const uint4*>(xp + k);
    unsigned uu[4] = {u.x, u.y, u.z, u.w};
    float xf[8];
    #pragma unroll
    for (int q = 0; q < 4; ++q) {
      xf[2 * q]     = __uint_as_float(uu[q] << 16);
      xf[2 * q + 1] = __uint_as_float(uu[q] & 0xFFFF0000u);
    }
    #pragma unroll
    for (int v = 0; v < 8; ++v) {
      const float* wp = wv + jobs.wslot[v] * 256 + k;
      #pragma unroll
      for (int q = 0; q < 8; ++q) acc[v] += xf[q] * wp[q];
    }
  }
  #pragma unroll
  for (int v = 0; v < 8; ++v) outBase[jobs.outOff[v] + i] = acc[v];
}

// ================= CSR build =================
struct RelIdx { const int* src[NREL]; const int* dst[NREL]; };

// XCD-pinned (measured r11: WRITE amplification 56MB -> gone): blockIdx.x & 7
// selects XCD (round-robin dispatch); relation r handled only by XCD r.
__global__ void hist_k(RelIdx ri, int* __restrict__ counts) {
  int xcd = blockIdx.x & 7;
  if (xcd >= NREL) return;
  int e = (blockIdx.x >> 3) * 256 + threadIdx.x;
  if (e >= NE) return;
  atomicAdd(&counts[xcd * RPSTR + ri.dst[xcd][e]], 1);
}
__global__ __launch_bounds__(256) void scan_blk(const int* __restrict__ in,
                                                int* __restrict__ partial,
                                                int* __restrict__ bsum, int n)
{
  __shared__ int ts[256];
  int t = threadIdx.x;
  int base = blockIdx.x * 1024 + t * 4;
  int v[4];
  #pragma unroll
  for (int i = 0; i < 4; ++i) v[i] = (base + i < n) ? in[base + i] : 0;
  int s = v[0] + v[1] + v[2] + v[3];
  ts[t] = s; __syncthreads();
  for (int off = 1; off < 256; off <<= 1) {
    int x = (t >= off) ? ts[t - off] : 0;
    __syncthreads();
    ts[t] += x;
    __syncthreads();
  }
  int run = ts[t] - s;
  #pragma unroll
  for (int i = 0; i < 4; ++i) {
    if (base + i < n) partial[base + i] = run;
    run += v[i];
  }
  if (t == 255) bsum[blockIdx.x] = ts[255];
}
__global__ __launch_bounds__(512) void scan_fin(const int* __restrict__ partial,
                                                const int* __restrict__ bsum,
                                                int* __restrict__ rowptr,
                                                int* __restrict__ cursor, int n)
{
  __shared__ int ts[512];
  int t = threadIdx.x;
  ts[t] = (t < (int)blockIdx.x) ? bsum[t] : 0;   // nb <= 512
  __syncthreads();
  #pragma unroll
  for (int off = 256; off; off >>= 1) {
    if (t < off) ts[t] += ts[t + off];
    __syncthreads();
  }
  int base = ts[0];
  #pragma unroll
  for (int i = 0; i < 2; ++i) {
    int idx = blockIdx.x * 1024 + t + i * 512;
    if (idx < n) {
      int v = partial[idx] + base;
      rowptr[idx] = v; cursor[idx] = v;
    }
  }
}
// XCD-pinned scatter (see hist_k)
__global__ void fill_k(RelIdx ri, int* __restrict__ cursor, int* __restrict__ colsrc) {
  int xcd = blockIdx.x & 7;
  if (xcd >= NREL) return;
  int e = (blockIdx.x >> 3) * 256 + threadIdx.x;
  if (e >= NE) return;
  int d = ri.dst[xcd][e];
  int pos = atomicAdd(&cursor[xcd * RPSTR + d], 1);
  colsrc[pos] = ri.src[xcd][e];
}

// ==== PV gather + FUSED in-register softmax ====
// Phase A (lanes = edges): gather alpha, 6-shfl max, exp, 6-shfl sum -> cn.
// Phase B (lanes = columns): measured-best gather; cf/si via __shfl broadcast.
struct PvRel { int rel; int rowptr_off; int as_off; int ad_off;
               const ushort_t* hs; int hst; int hoff; };
struct PvParams { PvRel dr[3]; PvRel di[4]; };

template<bool RELU>
__global__ __launch_bounds__(256) void pv_multi(
    PvParams P, const int* __restrict__ rowptr, const int* __restrict__ colsrc,
    const float* __restrict__ alphaB, const float* __restrict__ bias,
    ushort_t* __restrict__ outD, ushort_t* __restrict__ outI, int nbD)
{
  const int wave = threadIdx.x >> 6, lane = threadIdx.x & 63;
  const int c0 = 2 * lane;
  const bool isD = blockIdx.x < (unsigned)nbD;
  const int d = (isD ? blockIdx.x : blockIdx.x - nbD) * 4 + wave;
  const int Nd = isD ? NDRUG : NDIS;
  if (d >= Nd) return;
  const int nr = isD ? 3 : 4;
  float acc0 = 0.f, acc1 = 0.f;

  #pragma unroll
  for (int q = 0; q < 4; ++q) {
    if (q >= nr) break;
    const PvRel R = isD ? P.dr[q] : P.di[q];
    acc0 += bias[R.rel * HID + c0];
    acc1 += bias[R.rel * HID + c0 + 1];
    const int beg = rowptr[R.rowptr_off + d];
    const int end = rowptr[R.rowptr_off + d + 1];
    const int deg = end - beg;
    if (deg == 0) continue;
    const float ad = alphaB[R.ad_off + d];
    const float* as = alphaB + R.as_off;
    const ushort_t* hsb = R.hs + R.hoff + c0;
    const int hst = R.hst;

    if (deg <= 64) {
      // phase A: softmax across lanes (deg wave-uniform -> no wave divergence)
      int s = 0; float a = -1e30f;
      if (lane < deg) {
        s = colsrc[beg + lane];
        float t = as[s] + ad;
        a = t > 0.f ? t : 0.2f * t;
      }
      float m = a;
      #pragma unroll
      for (int off = 32; off; off >>= 1) m = fmaxf(m, __shfl_xor(m, off));
      float ex = (lane < deg) ? __expf(a - m) : 0.f;
      float sum = ex;
      #pragma unroll
      for (int off = 32; off; off >>= 1) sum += __shfl_xor(sum, off);
      const float cn = ex * (1.f / (sum + 1e-16f));   // 0 in lanes >= deg

      // phase B: gather (4-edge unroll, 2 cols/lane — measured-best r4/r10)
      for (int c = 0; c < deg; c += 4) {
        float cf[4]; int si[4];
        #pragma unroll
        for (int j = 0; j < 4; ++j) {
          int idx = c + j;
          cf[j] = (idx < deg) ? __shfl(cn, idx & 63) : 0.f;
          si[j] = __shfl(s, idx & 63);   // s=0 in tail lanes -> valid addr, cf=0
        }
        ushort2 hv[4];
        #pragma unroll
        for (int j = 0; j < 4; ++j)
          hv[j] = *reinterpret_cast<const ushort2*>(hsb + (size_t)si[j] * hst);
        #pragma unroll
        for (int j = 0; j < 4; ++j) {
          acc0 += cf[j] * bf2f(hv[j].x);
          acc1 += cf[j] * bf2f(hv[j].y);
        }
      }
    } else {
      // rare fallback: deg > 64 (3-pass)
      float m = -1e30f;
      for (int i = beg + lane; i < end; i += 64) {
        float t = as[colsrc[i]] + ad;
        t = t > 0.f ? t : 0.2f * t;
        m = fmaxf(m, t);
      }
      #pragma unroll
      for (int off = 32; off; off >>= 1) m = fmaxf(m, __shfl_xor(m, off));
      float sum = 0.f;
      for (int i = beg + lane; i < end; i += 64) {
        float t = as[colsrc[i]] + ad;
        t = t > 0.f ? t : 0.2f * t;
        sum += __expf(t - m);
      }
      #pragma unroll
      for (int off = 32; off; off >>= 1) sum += __shfl_xor(sum, off);
      const float inv = 1.f / (sum + 1e-16f);
      for (int cb = beg; cb < end; cb += 64) {
        int n = min(64, end - cb);
        int s = 0; float cn = 0.f;
        if (lane < n) {
          s = colsrc[cb + lane];
          float t = as[s] + ad;
          t = t > 0.f ? t : 0.2f * t;
          cn = __expf(t - m) * inv;
        }
        for (int c = 0; c < n; c += 4) {
          float cf[4]; int si[4];
          #pragma unroll
          for (int j = 0; j < 4; ++j) {
            int idx = c + j;
            cf[j] = (idx < n) ? __shfl(cn, idx & 63) : 0.f;
            si[j] = __shfl(s, idx & 63);
          }
          ushort2 hv[4];
          #pragma unroll
          for (int j = 0; j < 4; ++j)
            hv[j] = *reinterpret_cast<const ushort2*>(hsb + (size_t)si[j] * hst);
          #pragma unroll
          for (int j = 0; j < 4; ++j) {
            acc0 += cf[j] * bf2f(hv[j].x);
            acc1 += cf[j] * bf2f(hv[j].y);
          }
        }
      }
    }
  }
  if (RELU) { acc0 = fmaxf(acc0, 0.f); acc1 = fmaxf(acc1, 0.f); }
  ushort2 o; o.x = f2bf(acc0); o.y = f2bf(acc1);
  ushort_t* out = isD ? outD : outI;
  *reinterpret_cast<ushort2*>(out + (size_t)d * HID + c0) = o;
}

// ================= host =================
static const int DSTh[NREL] = {1, 0, 1, 0, 1, 1, 0};

struct WsPlan {
  ushort_t *xdb1, *xib1, *xd1b, *xi1b, *xd2b, *xi2b;
  ushort_t *hs_d, *hs_i, *wcatT_d, *wcatT_i, *wfinT_d, *wfinT_i;
  float *alphaB, *wv;
  int *counts, *rowptr, *cursor, *colsrc, *bsum;
  size_t total_bytes;
};

static WsPlan plan_ws(void* d_ws) {
  WsPlan p;
  ushort_t* s = (ushort_t*)d_ws;
  p.xdb1 = s;     s += (size_t)NDRUG * 256;
  p.xib1 = s;     s += (size_t)NDIS * 256;
  p.xd1b = s;     s += (size_t)NDRUG * HID;
  p.xi1b = s;     s += (size_t)NDIS * HID;
  p.hs_d = s;     s += (size_t)NDRUG * 384;
  p.hs_i = s;     s += (size_t)NDIS * 512;
  p.wcatT_d = s;  s += 384 * 256;
  p.wcatT_i = s;  s += 512 * 256;
  p.wfinT_d = s;  s += 128 * 128;
  p.wfinT_i = s;  s += 128 * 128;
  p.xd2b = p.xdb1;   // alias: xdb1 dead after L1 GEMM/alpha
  p.xi2b = p.xib1;
  float* f = (float*)s;
  p.alphaB = f;   f += (size_t)15 * NDIS;   // 14 rows + 1 dummy
  p.wv = f;       f += 14 * 256;
  int* q = (int*)f;
  p.counts = q;   q += NS_TOT;
  p.rowptr = q;   q += NS_TOT;
  p.cursor = q;   q += NS_TOT;
  p.colsrc = q;   q += NREL * NE;
  p.bsum = q;     q += 512;
  p.total_bytes = (size_t)((char*)q - (char*)d_ws);
  return p;
}

static void run_layer(const ushort_t* XDb, const ushort_t* XIb, int K,
                      const float* Wsrc, const float* Wdst,
                      const float* as_, const float* ad_, const float* bias,
                      ushort_t* outDb, ushort_t* outIb, bool relu,
                      const WsPlan& p, hipStream_t stream)
{
  int4 rd = make_int4(0, 2, 6, 0);
  int4 ri4 = make_int4(1, 3, 4, 5);
  build_wcat2<<<(K * 896 + 255) / 256, 256, 0, stream>>>(
      Wsrc, p.wcatT_d, 384, rd, Wsrc, p.wcatT_i, 512, ri4, K);
  wvec_kernel<<<dim3(14, K / 4), 256, 0, stream>>>(Wsrc, as_, Wdst, ad_, p.wv, K);

  AlphaJobs jd = {};
  jd.wslot[0] = 0;     jd.outOff[0] = 0 * NDIS;
  jd.wslot[1] = 2;     jd.outOff[1] = 2 * NDIS;
  jd.wslot[2] = 6;     jd.outOff[2] = 6 * NDIS;
  jd.wslot[3] = 7 + 1; jd.outOff[3] = (7 + 1) * NDIS;
  jd.wslot[4] = 7 + 3; jd.outOff[4] = (7 + 3) * NDIS;
  jd.wslot[5] = 7 + 6; jd.outOff[5] = (7 + 6) * NDIS;
  jd.wslot[6] = 0;     jd.outOff[6] = 14 * NDIS;   // dummy
  jd.wslot[7] = 0;     jd.outOff[7] = 14 * NDIS;   // dummy
  AlphaJobs ji = {};
  ji.wslot[0] = 1;     ji.outOff[0] = 1 * NDIS;
  ji.wslot[1] = 3;     ji.outOff[1] = 3 * NDIS;
  ji.wslot[2] = 4;     ji.outOff[2] = 4 * NDIS;
  ji.wslot[3] = 5;     ji.outOff[3] = 5 * NDIS;
  ji.wslot[4] = 7 + 0; ji.outOff[4] = (7 + 0) * NDIS;
  ji.wslot[5] = 7 + 2; ji.outOff[5] = (7 + 2) * NDIS;
  ji.wslot[6] = 7 + 4; ji.outOff[6] = (7 + 4) * NDIS;
  ji.wslot[7] = 7 + 5; ji.outOff[7] = (7 + 5) * NDIS;
  int gbD = (NDRUG + 255) / 256, gbI = (NDIS + 255) / 256;
  if (K == 256)
    alpha_dual<256><<<gbD + gbI, 256, 0, stream>>>(XDb, XIb, p.wv, p.alphaB, jd, ji, gbD);
  else
    alpha_dual<128><<<gbD + gbI, 256, 0, stream>>>(XDb, XIb, p.wv, p.alphaB, jd, ji, gbD);

  // hs GEMMs (both node types, one dispatch; 128x128 tiles)
  GemmJob g0 = {XDb, p.wcatT_d, nullptr, p.hs_d, NDRUG, 384};
  GemmJob g1 = {XIb, p.wcatT_i, nullptr, p.hs_i, NDIS, 512};
  int gx0 = (NDRUG + 127) / 128, gx1 = (NDIS + 127) / 128;
  gemm_dual<false, false, true><<<dim3(gx0 + gx1, 4), 256, 0, stream>>>(g0, g1, gx0, K);

  // PV gather with fused softmax (coef_k deleted)
  PvParams P;
  P.dr[0] = {1, 1 * RPSTR, 1 * NDIS, (NREL + 1) * NDIS, p.hs_i, 512, 0};
  P.dr[1] = {3, 3 * RPSTR, 3 * NDIS, (NREL + 3) * NDIS, p.hs_i, 512, 128};
  P.dr[2] = {6, 6 * RPSTR, 6 * NDIS, (NREL + 6) * NDIS, p.hs_d, 384, 256};
  P.di[0] = {0, 0 * RPSTR, 0 * NDIS, (NREL + 0) * NDIS, p.hs_d, 384, 0};
  P.di[1] = {2, 2 * RPSTR, 2 * NDIS, (NREL + 2) * NDIS, p.hs_d, 384, 128};
  P.di[2] = {4, 4 * RPSTR, 4 * NDIS, (NREL + 4) * NDIS, p.hs_i, 512, 256};
  P.di[3] = {5, 5 * RPSTR, 5 * NDIS, (NREL + 5) * NDIS, p.hs_i, 512, 384};
  int nbD = (NDRUG + 3) / 4, nbI = (NDIS + 3) / 4;
  if (relu)
    pv_multi<true><<<nbD + nbI, 256, 0, stream>>>(
        P, p.rowptr, p.colsrc, p.alphaB, bias, outDb, outIb, nbD);
  else
    pv_multi<false><<<nbD + nbI, 256, 0, stream>>>(
        P, p.rowptr, p.colsrc, p.alphaB, bias, outDb, outIb, nbD);
}

extern "C" void kernel_launch(void* const* d_in, const int* in_sizes, int n_in,
                              void* d_out, int out_size, void* d_ws, size_t ws_size,
                              hipStream_t stream) {
  const float* x_drug = (const float*)d_in[0];
  const float* x_dis  = (const float*)d_in[1];
  RelIdx ri;
  for (int r = 0; r < NREL; ++r) {
    const int* e = (const int*)d_in[2 + r];
    ri.src[r] = e; ri.dst[r] = e + NE;
  }
  const float* W1s = (const float*)d_in[9];
  const float* W1d = (const float*)d_in[10];
  const float* a1s = (const float*)d_in[11];
  const float* a1d = (const float*)d_in[12];
  const float* b1  = (const float*)d_in[13];
  const float* W2s = (const float*)d_in[14];
  const float* W2d = (const float*)d_in[15];
  const float* a2s = (const float*)d_in[16];
  const float* a2d = (const float*)d_in[17];
  const float* b2  = (const float*)d_in[18];
  const float* Wdr = (const float*)d_in[19];
  const float* bdr = (const float*)d_in[20];
  const float* Wdi = (const float*)d_in[21];
  const float* bdi = (const float*)d_in[22];

  WsPlan p = plan_ws(d_ws);
  if (p.total_bytes > ws_size) return;

  cvt2_f32_bf16<<<((NDRUG + NDIS) * 256 / 8 + 255) / 256, 256, 0, stream>>>(
      x_drug, p.xdb1, NDRUG * 256 / 8, x_dis, p.xib1, NDIS * 256 / 8);

  // CSR build (reused by both layers); hist/fill XCD-pinned per relation
  hipMemsetAsync(p.counts, 0, NS_TOT * sizeof(int), stream);
  hist_k<<<8 * CPX, 256, 0, stream>>>(ri, p.counts);
  int nb = (NS_TOT + 1023) / 1024;
  scan_blk<<<nb, 256, 0, stream>>>(p.counts, p.cursor, p.bsum, NS_TOT);
  scan_fin<<<nb, 512, 0, stream>>>(p.cursor, p.bsum, p.rowptr, p.cursor, NS_TOT);
  fill_k<<<8 * CPX, 256, 0, stream>>>(ri, p.cursor, p.colsrc);

  // Layer 1 (K=256, relu), Layer 2 (K=128)
  run_layer(p.xdb1, p.xib1, 256, W1s, W1d, a1s, a1d, b1, p.xd1b, p.xi1b, true, p, stream);
  run_layer(p.xd1b, p.xi1b, 128, W2s, W2d, a2s, a2d, b2, p.xd2b, p.xi2b, false, p, stream);

  // final linear + bias + relu -> d_out (f32)
  int4 r0 = make_int4(0, 0, 0, 0);
  build_wcat2<<<(128 * 128 * 2 + 255) / 256, 256, 0, stream>>>(
      Wdr, p.wfinT_d, 128, r0, Wdi, p.wfinT_i, 128, r0, 128);
  float* out = (float*)d_out;
  GemmJob f0 = {p.xd2b, p.wfinT_d, bdr, out, NDRUG, 128};
  GemmJob f1 = {p.xi2b, p.wfinT_i, bdi, out + (size_t)NDRUG * HID, NDIS, 128};
  int gx0 = (NDRUG + 127) / 128, gx1 = (NDIS + 127) / 128;
  gemm_dual<true, true, false><<<dim3(gx0 + gx1, 1), 256, 0, stream>>>(f0, f1, gx0, 128);
}

// Round 13
// 425.112 us; speedup vs baseline: 1.3198x; 1.0425x over previous
//
#include <hip/hip_runtime.h>
#include <stdint.h>

#define NDRUG 20000
#define NDIS  40000
#define HID   128
#define NE    150000
#define NREL  7
#define RPSTR (NDIS + 1)
#define NS_TOT (NREL * RPSTR)
#define CPX   ((NE + 255) / 256)   // edge-chunks per relation

typedef unsigned short ushort_t;
typedef __attribute__((ext_vector_type(8))) short bf16x8;
typedef __attribute__((ext_vector_type(4))) float f32x4;
typedef const __attribute__((address_space(1))) void gv_t;
typedef __attribute__((address_space(3))) void lv_t;

__device__ __forceinline__ ushort_t f2bf(float f) {
  unsigned u = __float_as_uint(f);
  u += 0x7FFFu + ((u >> 16) & 1u);          // RNE
  return (ushort_t)(u >> 16);
}
__device__ __forceinline__ float bf2f(ushort_t h) {
  return __uint_as_float(((unsigned)h) << 16);
}

// ============ dual-job bf16 MFMA GEMM: C = A[M,K] @ BT[N,K]^T ============
// 128x128 tile, 4 waves, 2-phase prefetch (double-buffered LDS, 1 barrier/step).
struct GemmJob { const ushort_t* A; const ushort_t* BT; const float* bias; void* C; int M, N; };

template<bool BIAS, bool RELU, bool BF16OUT>
__global__ __launch_bounds__(256) void gemm_dual(GemmJob j0, GemmJob j1, int gx0, int K)
{
  __shared__ ushort_t As[2][128 * 32];
  __shared__ ushort_t Bs[2][128 * 32];
  const bool first = blockIdx.x < (unsigned)gx0;
  const GemmJob J = first ? j0 : j1;
  const int bx = first ? blockIdx.x : blockIdx.x - gx0;
  if ((int)blockIdx.y * 128 >= J.N) return;   // uniform exit, before any sync
  const int tid = threadIdx.x;
  const int m0 = bx * 128;
  const int n0 = blockIdx.y * 128;
  const int wave = tid >> 6, lane = tid & 63;
  const int wm = wave & 1, wn = wave >> 1;
  const int l15 = lane & 15, lk = lane >> 4;

  const int rowS = wave * 16 + (lane >> 2);
  const int chunk = (lane & 3) * 8;
  const ushort_t* ga0 = J.A + (size_t)min(m0 + rowS, J.M - 1) * K + chunk;
  const ushort_t* ga1 = J.A + (size_t)min(m0 + rowS + 64, J.M - 1) * K + chunk;
  const ushort_t* gb0 = J.BT + (size_t)(n0 + rowS) * K + chunk;
  const ushort_t* gb1 = J.BT + (size_t)(n0 + rowS + 64) * K + chunk;

#define GEMM_STAGE(buf, koff)                                                              \
  do {                                                                                     \
    __builtin_amdgcn_global_load_lds((gv_t*)(ga0 + (koff)), (lv_t*)(&As[buf][wave * 512]), 16, 0, 0);        \
    __builtin_amdgcn_global_load_lds((gv_t*)(ga1 + (koff)), (lv_t*)(&As[buf][wave * 512 + 2048]), 16, 0, 0); \
    __builtin_amdgcn_global_load_lds((gv_t*)(gb0 + (koff)), (lv_t*)(&Bs[buf][wave * 512]), 16, 0, 0);        \
    __builtin_amdgcn_global_load_lds((gv_t*)(gb1 + (koff)), (lv_t*)(&Bs[buf][wave * 512 + 2048]), 16, 0, 0); \
  } while (0)

  f32x4 acc[4][4] = {};
  const int nt = K >> 5;

  GEMM_STAGE(0, 0);
  __syncthreads();                       // tile 0 landed

  for (int t = 0; t < nt; ++t) {
    if (t + 1 < nt) GEMM_STAGE((t + 1) & 1, (t + 1) * 32);
    const ushort_t* Ab = As[t & 1];
    const ushort_t* Bb = Bs[t & 1];
    bf16x8 af[4], bfg[4];
    #pragma unroll
    for (int m = 0; m < 4; ++m)
      af[m] = *reinterpret_cast<const bf16x8*>(&Ab[(wm * 64 + m * 16 + l15) * 32 + lk * 8]);
    #pragma unroll
    for (int n = 0; n < 4; ++n)
      bfg[n] = *reinterpret_cast<const bf16x8*>(&Bb[(wn * 64 + n * 16 + l15) * 32 + lk * 8]);
    #pragma unroll
    for (int m = 0; m < 4; ++m)
      #pragma unroll
      for (int n = 0; n < 4; ++n)
        acc[m][n] = __builtin_amdgcn_mfma_f32_16x16x32_bf16(af[m], bfg[n], acc[m][n], 0, 0, 0);
    __syncthreads();
  }
#undef GEMM_STAGE

  #pragma unroll
  for (int m = 0; m < 4; ++m) {
    int rbase = m0 + wm * 64 + m * 16 + lk * 4;
    #pragma unroll
    for (int n = 0; n < 4; ++n) {
      int col = n0 + wn * 64 + n * 16 + l15;
      float bv = 0.f;
      if (BIAS) bv = J.bias[col];
      #pragma unroll
      for (int j = 0; j < 4; ++j) {
        int row = rbase + j;
        if (row >= J.M) continue;
        float v = acc[m][n][j] + bv;
        if (RELU) v = fmaxf(v, 0.f);
        if (BF16OUT) ((ushort_t*)J.C)[(size_t)row * J.N + col] = f2bf(v);
        else         ((float*)J.C)[(size_t)row * J.N + col] = v;
      }
    }
  }
}

// ================= weight prep (two outputs in one dispatch) =================
__global__ void build_wcat2(const float* __restrict__ WA, ushort_t* __restrict__ outA,
                            int ncolA, int4 relsA,
                            const float* __restrict__ WB, ushort_t* __restrict__ outB,
                            int ncolB, int4 relsB, int K)
{
  int id = blockIdx.x * 256 + threadIdx.x;
  const float* W; ushort_t* out; int ncol; int4 rels;
  int totA = K * ncolA;
  if (id < totA) { W = WA; out = outA; ncol = ncolA; rels = relsA; }
  else {
    id -= totA;
    if (id >= K * ncolB) return;
    W = WB; out = outB; ncol = ncolB; rels = relsB;
  }
  int k = id / ncol, c = id - k * ncol;
  int rr = (&rels.x)[c >> 7];
  out[(size_t)c * K + k] = f2bf(W[((size_t)rr * K + k) * HID + (c & 127)]);
}

// wv[slot][k] = sum_j W[r][k][j] * a[r][j]   (slot<7: src, else dst)
__global__ __launch_bounds__(256) void wvec_kernel(
    const float* __restrict__ Wsrc, const float* __restrict__ as_,
    const float* __restrict__ Wdst, const float* __restrict__ ad_,
    float* __restrict__ wv, int K)
{
  int slot = blockIdx.x;
  int r = slot % NREL;
  const float* W = (slot < NREL ? Wsrc : Wdst) + (size_t)r * K * HID;
  const float* a = (slot < NREL ? as_ : ad_) + r * HID;
  int wave = threadIdx.x >> 6, lane = threadIdx.x & 63;
  int k = blockIdx.y * 4 + wave;
  if (k >= K) return;
  float s = W[(size_t)k * HID + lane] * a[lane]
          + W[(size_t)k * HID + 64 + lane] * a[64 + lane];
  #pragma unroll
  for (int off = 32; off; off >>= 1) s += __shfl_xor(s, off);
  if (lane == 0) wv[slot * 256 + k] = s;
}

// ================= f32 -> bf16 convert (two tensors, one dispatch) =================
__global__ void cvt2_f32_bf16(const float* __restrict__ inA, ushort_t* __restrict__ outA, int n8A,
                              const float* __restrict__ inB, ushort_t* __restrict__ outB, int n8B)
{
  int i = blockIdx.x * 256 + threadIdx.x;
  const float* in; ushort_t* out;
  if (i < n8A) { in = inA; out = outA; }
  else {
    i -= n8A;
    if (i >= n8B) return;
    in = inB; out = outB;
  }
  float4 a = reinterpret_cast<const float4*>(in)[2 * i];
  float4 b = reinterpret_cast<const float4*>(in)[2 * i + 1];
  ushort_t r[8] = {f2bf(a.x), f2bf(a.y), f2bf(a.z), f2bf(a.w),
                   f2bf(b.x), f2bf(b.y), f2bf(b.z), f2bf(b.w)};
  reinterpret_cast<uint4*>(out)[i] = *reinterpret_cast<uint4*>(r);
}

// ================= batched alpha GEMV, both node types in one dispatch =================
struct AlphaJobs { int wslot[8]; int outOff[8]; };

template<int K>
__global__ __launch_bounds__(256) void alpha_dual(
    const ushort_t* __restrict__ XD, const ushort_t* __restrict__ XI,
    const float* __restrict__ wv, float* __restrict__ outBase,
    AlphaJobs jd, AlphaJobs ji, int gbD)
{
  const bool isD = blockIdx.x < (unsigned)gbD;
  const ushort_t* X = isD ? XD : XI;
  const int N = isD ? NDRUG : NDIS;
  const AlphaJobs jobs = isD ? jd : ji;
  int i = (isD ? blockIdx.x : blockIdx.x - gbD) * 256 + threadIdx.x;
  if (i >= N) return;
  float acc[8];
  #pragma unroll
  for (int v = 0; v < 8; ++v) acc[v] = 0.f;
  const ushort_t* xp = X + (size_t)i * K;
  for (int k = 0; k < K; k += 8) {
    uint4 u = *reinterpret_cast<const uint4*>(xp + k);
    unsigned uu[4] = {u.x, u.y, u.z, u.w};
    float xf[8];
    #pragma unroll
    for (int q = 0; q < 4; ++q) {
      xf[2 * q]     = __uint_as_float(uu[q] << 16);
      xf[2 * q + 1] = __uint_as_float(uu[q] & 0xFFFF0000u);
    }
    #pragma unroll
    for (int v = 0; v < 8; ++v) {
      const float* wp = wv + jobs.wslot[v] * 256 + k;
      #pragma unroll
      for (int q = 0; q < 8; ++q) acc[v] += xf[q] * wp[q];
    }
  }
  #pragma unroll
  for (int v = 0; v < 8; ++v) outBase[jobs.outOff[v] + i] = acc[v];
}

// ================= CSR build =================
struct RelIdx { const int* src[NREL]; const int* dst[NREL]; };

// XCD-pinned (measured r11: WRITE amplification 56MB -> gone): blockIdx.x & 7
// selects XCD (round-robin dispatch); relation r handled only by XCD r.
__global__ void hist_k(RelIdx ri, int* __restrict__ counts) {
  int xcd = blockIdx.x & 7;
  if (xcd >= NREL) return;
  int e = (blockIdx.x >> 3) * 256 + threadIdx.x;
  if (e >= NE) return;
  atomicAdd(&counts[xcd * RPSTR + ri.dst[xcd][e]], 1);
}
__global__ __launch_bounds__(256) void scan_blk(const int* __restrict__ in,
                                                int* __restrict__ partial,
                                                int* __restrict__ bsum, int n)
{
  __shared__ int ts[256];
  int t = threadIdx.x;
  int base = blockIdx.x * 1024 + t * 4;
  int v[4];
  #pragma unroll
  for (int i = 0; i < 4; ++i) v[i] = (base + i < n) ? in[base + i] : 0;
  int s = v[0] + v[1] + v[2] + v[3];
  ts[t] = s; __syncthreads();
  for (int off = 1; off < 256; off <<= 1) {
    int x = (t >= off) ? ts[t - off] : 0;
    __syncthreads();
    ts[t] += x;
    __syncthreads();
  }
  int run = ts[t] - s;
  #pragma unroll
  for (int i = 0; i < 4; ++i) {
    if (base + i < n) partial[base + i] = run;
    run += v[i];
  }
  if (t == 255) bsum[blockIdx.x] = ts[255];
}
__global__ __launch_bounds__(512) void scan_fin(const int* __restrict__ partial,
                                                const int* __restrict__ bsum,
                                                int* __restrict__ rowptr,
                                                int* __restrict__ cursor, int n)
{
  __shared__ int ts[512];
  int t = threadIdx.x;
  ts[t] = (t < (int)blockIdx.x) ? bsum[t] : 0;   // nb <= 512
  __syncthreads();
  #pragma unroll
  for (int off = 256; off; off >>= 1) {
    if (t < off) ts[t] += ts[t + off];
    __syncthreads();
  }
  int base = ts[0];
  #pragma unroll
  for (int i = 0; i < 2; ++i) {
    int idx = blockIdx.x * 1024 + t + i * 512;
    if (idx < n) {
      int v = partial[idx] + base;
      rowptr[idx] = v; cursor[idx] = v;
    }
  }
}
// XCD-pinned scatter (see hist_k)
__global__ void fill_k(RelIdx ri, int* __restrict__ cursor, int* __restrict__ colsrc) {
  int xcd = blockIdx.x & 7;
  if (xcd >= NREL) return;
  int e = (blockIdx.x >> 3) * 256 + threadIdx.x;
  if (e >= NE) return;
  int d = ri.dst[xcd][e];
  int pos = atomicAdd(&cursor[xcd * RPSTR + d], 1);
  colsrc[pos] = ri.src[xcd][e];
}

// ==== PV gather + fused in-register softmax (r13: batched phase A, readlane) ====
struct PvRel { int rel; int rowptr_off; int as_off; int ad_off;
               const ushort_t* hs; int hst; int hoff; };
struct PvParams { PvRel dr[3]; PvRel di[4]; };

template<bool RELU>
__global__ __launch_bounds__(256) void pv_multi(
    PvParams P, const int* __restrict__ rowptr, const int* __restrict__ colsrc,
    const float* __restrict__ alphaB, const float* __restrict__ bias,
    ushort_t* __restrict__ outD, ushort_t* __restrict__ outI, int nbD)
{
  const int wave = threadIdx.x >> 6, lane = threadIdx.x & 63;
  const int c0 = 2 * lane;
  const bool isD = blockIdx.x < (unsigned)nbD;
  const int d = (isD ? blockIdx.x : blockIdx.x - nbD) * 4 + wave;
  const int Nd = isD ? NDRUG : NDIS;
  if (d >= Nd) return;        // wave-uniform (d depends on block+wave only)
  const int nr = isD ? 3 : 4;
  float acc0 = 0.f, acc1 = 0.f;

  // ---- phase A (batched across relations for MLP) ----
  int beg_[4], deg_[4];
  float ad_[4];
  #pragma unroll
  for (int q = 0; q < 4; ++q) {
    deg_[q] = 0; beg_[q] = 0; ad_[q] = 0.f;
    if (q >= nr) continue;
    const PvRel R = isD ? P.dr[q] : P.di[q];
    acc0 += bias[R.rel * HID + c0];
    acc1 += bias[R.rel * HID + c0 + 1];
    beg_[q] = rowptr[R.rowptr_off + d];
    deg_[q] = rowptr[R.rowptr_off + d + 1] - beg_[q];
    ad_[q]  = alphaB[R.ad_off + d];
  }
  int s_[4];                        // 4 independent colsrc gathers in flight
  #pragma unroll
  for (int q = 0; q < 4; ++q)
    s_[q] = (q < nr && deg_[q] <= 64 && lane < deg_[q]) ? colsrc[beg_[q] + lane] : 0;
  float a_[4];                      // 4 independent alpha gathers in flight
  #pragma unroll
  for (int q = 0; q < 4; ++q) {
    a_[q] = -1e30f;
    if (q < nr && deg_[q] <= 64 && lane < deg_[q]) {
      const PvRel R = isD ? P.dr[q] : P.di[q];
      float t = alphaB[R.as_off + s_[q]] + ad_[q];
      a_[q] = t > 0.f ? t : 0.2f * t;
    }
  }
  // softmax reduces (deg<=16: 4-step butterfly over lanes 0-15; else 6-step)
  float cn_[4];
  #pragma unroll
  for (int q = 0; q < 4; ++q) {
    cn_[q] = 0.f;
    const int dq = deg_[q];
    if (q >= nr || dq == 0 || dq > 64) continue;
    float m = a_[q];
    if (dq <= 16) {
      #pragma unroll
      for (int off = 8; off; off >>= 1) m = fmaxf(m, __shfl_xor(m, off));
    } else {
      #pragma unroll
      for (int off = 32; off; off >>= 1) m = fmaxf(m, __shfl_xor(m, off));
    }
    float ex = (lane < dq) ? __expf(a_[q] - m) : 0.f;
    float sum = ex;
    if (dq <= 16) {
      #pragma unroll
      for (int off = 8; off; off >>= 1) sum += __shfl_xor(sum, off);
    } else {
      #pragma unroll
      for (int off = 32; off; off >>= 1) sum += __shfl_xor(sum, off);
    }
    cn_[q] = ex * (1.f / (sum + 1e-16f));   // 0 in lanes >= dq
  }

  // ---- phase B: gather; broadcasts via v_readlane (wave-uniform index) ----
  #pragma unroll
  for (int q = 0; q < 4; ++q) {
    if (q >= nr) break;
    const int dq = deg_[q];
    if (dq == 0) continue;
    const PvRel R = isD ? P.dr[q] : P.di[q];
    const ushort_t* hsb = R.hs + R.hoff + c0;
    const int hst = R.hst;

    if (dq <= 64) {
      const int sreg = s_[q];
      const int creg = __float_as_int(cn_[q]);
      for (int c = 0; c < dq; c += 4) {
        float cf[4]; int si[4];
        #pragma unroll
        for (int j = 0; j < 4; ++j) {
          int idx = c + j;                                   // wave-uniform
          si[j] = __builtin_amdgcn_readlane(sreg, idx & 63);
          int cb = __builtin_amdgcn_readlane(creg, idx & 63);
          cf[j] = (idx < dq) ? __int_as_float(cb) : 0.f;
        }
        ushort2 hv[4];
        #pragma unroll
        for (int j = 0; j < 4; ++j)
          hv[j] = *reinterpret_cast<const ushort2*>(hsb + (size_t)si[j] * hst);
        #pragma unroll
        for (int j = 0; j < 4; ++j) {
          acc0 += cf[j] * bf2f(hv[j].x);
          acc1 += cf[j] * bf2f(hv[j].y);
        }
      }
    } else {
      // rare fallback: deg > 64 (3-pass, shfl broadcasts)
      const int beg = beg_[q], end = beg_[q] + dq;
      const float ad = ad_[q];
      const float* as = alphaB + R.as_off;
      float m = -1e30f;
      for (int i = beg + lane; i < end; i += 64) {
        float t = as[colsrc[i]] + ad;
        t = t > 0.f ? t : 0.2f * t;
        m = fmaxf(m, t);
      }
      #pragma unroll
      for (int off = 32; off; off >>= 1) m = fmaxf(m, __shfl_xor(m, off));
      float sum = 0.f;
      for (int i = beg + lane; i < end; i += 64) {
        float t = as[colsrc[i]] + ad;
        t = t > 0.f ? t : 0.2f * t;
        sum += __expf(t - m);
      }
      #pragma unroll
      for (int off = 32; off; off >>= 1) sum += __shfl_xor(sum, off);
      const float inv = 1.f / (sum + 1e-16f);
      for (int cb = beg; cb < end; cb += 64) {
        int n = min(64, end - cb);
        int s = 0; float cn = 0.f;
        if (lane < n) {
          s = colsrc[cb + lane];
          float t = as[s] + ad;
          t = t > 0.f ? t : 0.2f * t;
          cn = __expf(t - m) * inv;
        }
        for (int c = 0; c < n; c += 4) {
          float cf[4]; int si[4];
          #pragma unroll
          for (int j = 0; j < 4; ++j) {
            int idx = c + j;
            si[j] = __builtin_amdgcn_readlane(s, idx & 63);
            int cb2 = __builtin_amdgcn_readlane(__float_as_int(cn), idx & 63);
            cf[j] = (idx < n) ? __int_as_float(cb2) : 0.f;
          }
          ushort2 hv[4];
          #pragma unroll
          for (int j = 0; j < 4; ++j)
            hv[j] = *reinterpret_cast<const ushort2*>(hsb + (size_t)si[j] * hst);
          #pragma unroll
          for (int j = 0; j < 4; ++j) {
            acc0 += cf[j] * bf2f(hv[j].x);
            acc1 += cf[j] * bf2f(hv[j].y);
          }
        }
      }
    }
  }
  if (RELU) { acc0 = fmaxf(acc0, 0.f); acc1 = fmaxf(acc1, 0.f); }
  ushort2 o; o.x = f2bf(acc0); o.y = f2bf(acc1);
  ushort_t* out = isD ? outD : outI;
  *reinterpret_cast<ushort2*>(out + (size_t)d * HID + c0) = o;
}

// ================= host =================
static const int DSTh[NREL] = {1, 0, 1, 0, 1, 1, 0};

struct WsPlan {
  ushort_t *xdb1, *xib1, *xd1b, *xi1b, *xd2b, *xi2b;
  ushort_t *hs_d, *hs_i, *wcatT_d, *wcatT_i, *wfinT_d, *wfinT_i;
  float *alphaB, *wv;
  int *counts, *rowptr, *cursor, *colsrc, *bsum;
  size_t total_bytes;
};

static WsPlan plan_ws(void* d_ws) {
  WsPlan p;
  ushort_t* s = (ushort_t*)d_ws;
  p.xdb1 = s;     s += (size_t)NDRUG * 256;
  p.xib1 = s;     s += (size_t)NDIS * 256;
  p.xd1b = s;     s += (size_t)NDRUG * HID;
  p.xi1b = s;     s += (size_t)NDIS * HID;
  p.hs_d = s;     s += (size_t)NDRUG * 384;
  p.hs_i = s;     s += (size_t)NDIS * 512;
  p.wcatT_d = s;  s += 384 * 256;
  p.wcatT_i = s;  s += 512 * 256;
  p.wfinT_d = s;  s += 128 * 128;
  p.wfinT_i = s;  s += 128 * 128;
  p.xd2b = p.xdb1;   // alias: xdb1 dead after L1 GEMM/alpha
  p.xi2b = p.xib1;
  float* f = (float*)s;
  p.alphaB = f;   f += (size_t)15 * NDIS;   // 14 rows + 1 dummy
  p.wv = f;       f += 14 * 256;
  int* q = (int*)f;
  p.counts = q;   q += NS_TOT;
  p.rowptr = q;   q += NS_TOT;
  p.cursor = q;   q += NS_TOT;
  p.colsrc = q;   q += NREL * NE;
  p.bsum = q;     q += 512;
  p.total_bytes = (size_t)((char*)q - (char*)d_ws);
  return p;
}

static void run_layer(const ushort_t* XDb, const ushort_t* XIb, int K,
                      const float* Wsrc, const float* Wdst,
                      const float* as_, const float* ad_, const float* bias,
                      ushort_t* outDb, ushort_t* outIb, bool relu,
                      const WsPlan& p, hipStream_t stream)
{
  int4 rd = make_int4(0, 2, 6, 0);
  int4 ri4 = make_int4(1, 3, 4, 5);
  build_wcat2<<<(K * 896 + 255) / 256, 256, 0, stream>>>(
      Wsrc, p.wcatT_d, 384, rd, Wsrc, p.wcatT_i, 512, ri4, K);
  wvec_kernel<<<dim3(14, K / 4), 256, 0, stream>>>(Wsrc, as_, Wdst, ad_, p.wv, K);

  AlphaJobs jd = {};
  jd.wslot[0] = 0;     jd.outOff[0] = 0 * NDIS;
  jd.wslot[1] = 2;     jd.outOff[1] = 2 * NDIS;
  jd.wslot[2] = 6;     jd.outOff[2] = 6 * NDIS;
  jd.wslot[3] = 7 + 1; jd.outOff[3] = (7 + 1) * NDIS;
  jd.wslot[4] = 7 + 3; jd.outOff[4] = (7 + 3) * NDIS;
  jd.wslot[5] = 7 + 6; jd.outOff[5] = (7 + 6) * NDIS;
  jd.wslot[6] = 0;     jd.outOff[6] = 14 * NDIS;   // dummy
  jd.wslot[7] = 0;     jd.outOff[7] = 14 * NDIS;   // dummy
  AlphaJobs ji = {};
  ji.wslot[0] = 1;     ji.outOff[0] = 1 * NDIS;
  ji.wslot[1] = 3;     ji.outOff[1] = 3 * NDIS;
  ji.wslot[2] = 4;     ji.outOff[2] = 4 * NDIS;
  ji.wslot[3] = 5;     ji.outOff[3] = 5 * NDIS;
  ji.wslot[4] = 7 + 0; ji.outOff[4] = (7 + 0) * NDIS;
  ji.wslot[5] = 7 + 2; ji.outOff[5] = (7 + 2) * NDIS;
  ji.wslot[6] = 7 + 4; ji.outOff[6] = (7 + 4) * NDIS;
  ji.wslot[7] = 7 + 5; ji.outOff[7] = (7 + 5) * NDIS;
  int gbD = (NDRUG + 255) / 256, gbI = (NDIS + 255) / 256;
  if (K == 256)
    alpha_dual<256><<<gbD + gbI, 256, 0, stream>>>(XDb, XIb, p.wv, p.alphaB, jd, ji, gbD);
  else
    alpha_dual<128><<<gbD + gbI, 256, 0, stream>>>(XDb, XIb, p.wv, p.alphaB, jd, ji, gbD);

  // hs GEMMs (both node types, one dispatch; 128x128 tiles)
  GemmJob g0 = {XDb, p.wcatT_d, nullptr, p.hs_d, NDRUG, 384};
  GemmJob g1 = {XIb, p.wcatT_i, nullptr, p.hs_i, NDIS, 512};
  int gx0 = (NDRUG + 127) / 128, gx1 = (NDIS + 127) / 128;
  gemm_dual<false, false, true><<<dim3(gx0 + gx1, 4), 256, 0, stream>>>(g0, g1, gx0, K);

  // PV gather with fused softmax
  PvParams P;
  P.dr[0] = {1, 1 * RPSTR, 1 * NDIS, (NREL + 1) * NDIS, p.hs_i, 512, 0};
  P.dr[1] = {3, 3 * RPSTR, 3 * NDIS, (NREL + 3) * NDIS, p.hs_i, 512, 128};
  P.dr[2] = {6, 6 * RPSTR, 6 * NDIS, (NREL + 6) * NDIS, p.hs_d, 384, 256};
  P.di[0] = {0, 0 * RPSTR, 0 * NDIS, (NREL + 0) * NDIS, p.hs_d, 384, 0};
  P.di[1] = {2, 2 * RPSTR, 2 * NDIS, (NREL + 2) * NDIS, p.hs_d, 384, 128};
  P.di[2] = {4, 4 * RPSTR, 4 * NDIS, (NREL + 4) * NDIS, p.hs_i, 512, 256};
  P.di[3] = {5, 5 * RPSTR, 5 * NDIS, (NREL + 5) * NDIS, p.hs_i, 512, 384};
  int nbD = (NDRUG + 3) / 4, nbI = (NDIS + 3) / 4;
  if (relu)
    pv_multi<true><<<nbD + nbI, 256, 0, stream>>>(
        P, p.rowptr, p.colsrc, p.alphaB, bias, outDb, outIb, nbD);
  else
    pv_multi<false><<<nbD + nbI, 256, 0, stream>>>(
        P, p.rowptr, p.colsrc, p.alphaB, bias, outDb, outIb, nbD);
}

extern "C" void kernel_launch(void* const* d_in, const int* in_sizes, int n_in,
                              void* d_out, int out_size, void* d_ws, size_t ws_size,
                              hipStream_t stream) {
  const float* x_drug = (const float*)d_in[0];
  const float* x_dis  = (const float*)d_in[1];
  RelIdx ri;
  for (int r = 0; r < NREL; ++r) {
    const int* e = (const int*)d_in[2 + r];
    ri.src[r] = e; ri.dst[r] = e + NE;
  }
  const float* W1s = (const float*)d_in[9];
  const float* W1d = (const float*)d_in[10];
  const float* a1s = (const float*)d_in[11];
  const float* a1d = (const float*)d_in[12];
  const float* b1  = (const float*)d_in[13];
  const float* W2s = (const float*)d_in[14];
  const float* W2d = (const float*)d_in[15];
  const float* a2s = (const float*)d_in[16];
  const float* a2d = (const float*)d_in[17];
  const float* b2  = (const float*)d_in[18];
  const float* Wdr = (const float*)d_in[19];
  const float* bdr = (const float*)d_in[20];
  const float* Wdi = (const float*)d_in[21];
  const float* bdi = (const float*)d_in[22];

  WsPlan p = plan_ws(d_ws);
  if (p.total_bytes > ws_size) return;

  cvt2_f32_bf16<<<((NDRUG + NDIS) * 256 / 8 + 255) / 256, 256, 0, stream>>>(
      x_drug, p.xdb1, NDRUG * 256 / 8, x_dis, p.xib1, NDIS * 256 / 8);

  // CSR build (reused by both layers); hist/fill XCD-pinned per relation
  hipMemsetAsync(p.counts, 0, NS_TOT * sizeof(int), stream);
  hist_k<<<8 * CPX, 256, 0, stream>>>(ri, p.counts);
  int nb = (NS_TOT + 1023) / 1024;
  scan_blk<<<nb, 256, 0, stream>>>(p.counts, p.cursor, p.bsum, NS_TOT);
  scan_fin<<<nb, 512, 0, stream>>>(p.cursor, p.bsum, p.rowptr, p.cursor, NS_TOT);
  fill_k<<<8 * CPX, 256, 0, stream>>>(ri, p.cursor, p.colsrc);

  // Layer 1 (K=256, relu), Layer 2 (K=128)
  run_layer(p.xdb1, p.xib1, 256, W1s, W1d, a1s, a1d, b1, p.xd1b, p.xi1b, true, p, stream);
  run_layer(p.xd1b, p.xi1b, 128, W2s, W2d, a2s, a2d, b2, p.xd2b, p.xi2b, false, p, stream);

  // final linear + bias + relu -> d_out (f32)
  int4 r0 = make_int4(0, 0, 0, 0);
  build_wcat2<<<(128 * 128 * 2 + 255) / 256, 256, 0, stream>>>(
      Wdr, p.wfinT_d, 128, r0, Wdi, p.wfinT_i, 128, r0, 128);
  float* out = (float*)d_out;
  GemmJob f0 = {p.xd2b, p.wfinT_d, bdr, out, NDRUG, 128};
  GemmJob f1 = {p.xi2b, p.wfinT_i, bdi, out + (size_t)NDRUG * HID, NDIS, 128};
  int gx0 = (NDRUG + 127) / 128, gx1 = (NDIS + 127) / 128;
  gemm_dual<true, true, false><<<dim3(gx0 + gx1, 1), 256, 0, stream>>>(f0, f1, gx0, 128);
}